// Round 4
// baseline (1868.679 us; speedup 1.0000x reference)
//
#include <hip/hip_runtime.h>

#define DEVINL __device__ __forceinline__

constexpr int NN = 4096, DD = 256, EE = 131072, HHD = 8, HIDN = 512, COEF_ = 7;
constexpr int KSPLIT = 2;
constexpr int PART_STRIDE = 34;  // m, l, o[32]

DEVINL float siluf(float x) { return x / (1.f + __expf(-x)); }

// ---------------- GCN graph part ----------------

__global__ void deg_k(const int* __restrict__ ei, float* __restrict__ deg) {
  int e = blockIdx.x * 256 + threadIdx.x;
  if (e < EE) atomicAdd(&deg[ei[e]], 1.0f);
}

__global__ void dis_k(float* __restrict__ deg) {
  int i = blockIdx.x * 256 + threadIdx.x;
  if (i < NN) deg[i] = rsqrtf(deg[i] + 1.0f);  // +1 self loop
}

__global__ __launch_bounds__(256) void selfinit_k(const float* __restrict__ x,
    const float* __restrict__ dis, float* __restrict__ aggr) {
  int i = blockIdx.x * 256 + threadIdx.x;  // < N*D
  int row = i >> 8;
  float dd = dis[row];
  aggr[i] = dd * dd * x[i];
}

__global__ __launch_bounds__(256) void scatter_k(const int* __restrict__ ei,
    const float* __restrict__ x, const float* __restrict__ dis, float* __restrict__ aggr) {
  int e = blockIdx.x * 4 + (threadIdx.x >> 6);
  if (e >= EE) return;
  int lane = threadIdx.x & 63;
  int s = ei[e], t = ei[EE + e];
  float nrm = dis[s] * dis[t];
  int d0 = lane * 4;
  const float4 xv = *(const float4*)(x + (size_t)s * DD + d0);
  float* ar = aggr + (size_t)t * DD + d0;
  atomicAdd(ar + 0, nrm * xv.x);
  atomicAdd(ar + 1, nrm * xv.y);
  atomicAdd(ar + 2, nrm * xv.z);
  atomicAdd(ar + 3, nrm * xv.w);
}

// ---------------- generic fp32 tiled GEMM: C[n,m] = A[n,k] @ W[m,k]^T (+bias) ----------------

template<bool SILU_A, bool SILU_OUT, bool ACCUM>
__global__ __launch_bounds__(256) void gemm_nt(const float* __restrict__ A,
    const float* __restrict__ W, const float* __restrict__ bias,
    float* __restrict__ C, int n, int m, int k)
{
  __shared__ float As[16][65];
  __shared__ float Ws[16][65];
  const int tid = threadIdx.x;
  const int tx = tid & 15, ty = tid >> 4;
  const int bn = blockIdx.x * 64, bm = blockIdx.y * 64;
  const int lr = tid >> 4;
  const int lc = tid & 15;
  float acc[4][4] = {};
  for (int kt = 0; kt < k; kt += 16) {
#pragma unroll
    for (int rr = 0; rr < 64; rr += 16) {
      float va = A[(size_t)(bn + lr + rr) * k + kt + lc];
      if (SILU_A) va = siluf(va);
      As[lc][lr + rr] = va;
      Ws[lc][lr + rr] = W[(size_t)(bm + lr + rr) * k + kt + lc];
    }
    __syncthreads();
#pragma unroll
    for (int kk = 0; kk < 16; ++kk) {
      float av[4], bv[4];
#pragma unroll
      for (int i = 0; i < 4; ++i) av[i] = As[kk][ty * 4 + i];
#pragma unroll
      for (int j = 0; j < 4; ++j) bv[j] = Ws[kk][tx * 4 + j];
#pragma unroll
      for (int i = 0; i < 4; ++i)
#pragma unroll
        for (int j = 0; j < 4; ++j)
          acc[i][j] = fmaf(av[i], bv[j], acc[i][j]);
    }
    __syncthreads();
  }
  float bv[4];
#pragma unroll
  for (int j = 0; j < 4; ++j) bv[j] = bias ? bias[bm + tx * 4 + j] : 0.f;
#pragma unroll
  for (int i = 0; i < 4; ++i) {
    size_t ro = (size_t)(bn + ty * 4 + i) * m + bm + tx * 4;
#pragma unroll
    for (int j = 0; j < 4; ++j) {
      float v = acc[i][j] + bv[j];
      if (ACCUM) v += C[ro + j];
      if (SILU_OUT) v = siluf(v);
      C[ro + j] = v;
    }
  }
}

// ---------------- LayerNorm ----------------

__global__ __launch_bounds__(256) void layernorm_k(const float* __restrict__ x,
    const float* __restrict__ g, const float* __restrict__ b, float* __restrict__ xn) {
  int row = blockIdx.x, t = threadIdx.x;
  float v = x[(size_t)row * DD + t];
  float s = v, sq = v * v;
#pragma unroll
  for (int o = 32; o > 0; o >>= 1) { s += __shfl_down(s, o); sq += __shfl_down(sq, o); }
  __shared__ float rs[4], rq[4];
  int wid = t >> 6, lane = t & 63;
  if (lane == 0) { rs[wid] = s; rq[wid] = sq; }
  __syncthreads();
  float S = rs[0] + rs[1] + rs[2] + rs[3];
  float SQ = rq[0] + rq[1] + rq[2] + rq[3];
  float mu = S * (1.f / 256.f);
  float var = SQ * (1.f / 256.f) - mu * mu;
  float inv = rsqrtf(var + 1e-5f);
  xn[(size_t)row * DD + t] = (v - mu) * inv * g[t] + b[t];
}

// ---------------- split-K flash attention (fp32) ----------------

__global__ __launch_bounds__(64) void flash_k(const float* __restrict__ qkv,
                                              float* __restrict__ part) {
  const int h = blockIdx.y, qb = blockIdx.x, kz = blockIdx.z;
  const int lane = threadIdx.x;
  const int n = qb * 64 + lane;
  const float* qr = qkv + (size_t)n * 768 + h * 32;
  float q[32];
#pragma unroll
  for (int d = 0; d < 32; d += 4) {
    float4 t4 = *(const float4*)&qr[d];
    q[d] = t4.x; q[d + 1] = t4.y; q[d + 2] = t4.z; q[d + 3] = t4.w;
  }
  float m = -1e30f, l = 0.f, o[32] = {};
  __shared__ float Ks[64][36];
  __shared__ float Vs[64][36];
  const int k0 = kz * (NN / KSPLIT), k1 = k0 + NN / KSPLIT;
  for (int t = k0; t < k1; t += 64) {
    __syncthreads();
    const float* kr = qkv + (size_t)(t + lane) * 768 + 256 + h * 32;
    const float* vr = qkv + (size_t)(t + lane) * 768 + 512 + h * 32;
#pragma unroll
    for (int d = 0; d < 32; d += 4) {
      *(float4*)&Ks[lane][d] = *(const float4*)&kr[d];
      *(float4*)&Vs[lane][d] = *(const float4*)&vr[d];
    }
    __syncthreads();
    for (int j = 0; j < 64; ++j) {
      float s = 0.f;
#pragma unroll
      for (int d = 0; d < 32; d += 4) {
        float4 kk4 = *(const float4*)&Ks[j][d];
        s = fmaf(q[d], kk4.x, s); s = fmaf(q[d + 1], kk4.y, s);
        s = fmaf(q[d + 2], kk4.z, s); s = fmaf(q[d + 3], kk4.w, s);
      }
      s *= 0.17677669529663687f;  // 1/sqrt(32)
      if (s > m) {
        float c = __expf(m - s);
        m = s;
        l = fmaf(l, c, 1.f);
#pragma unroll
        for (int d = 0; d < 32; d += 4) {
          float4 vv = *(const float4*)&Vs[j][d];
          o[d] = fmaf(o[d], c, vv.x); o[d + 1] = fmaf(o[d + 1], c, vv.y);
          o[d + 2] = fmaf(o[d + 2], c, vv.z); o[d + 3] = fmaf(o[d + 3], c, vv.w);
        }
      } else {
        float p = __expf(s - m);
        l += p;
#pragma unroll
        for (int d = 0; d < 32; d += 4) {
          float4 vv = *(const float4*)&Vs[j][d];
          o[d] = fmaf(p, vv.x, o[d]); o[d + 1] = fmaf(p, vv.y, o[d + 1]);
          o[d + 2] = fmaf(p, vv.z, o[d + 2]); o[d + 3] = fmaf(p, vv.w, o[d + 3]);
        }
      }
    }
  }
  float* P = part + ((size_t)(h * NN + n) * KSPLIT + kz) * PART_STRIDE;
  P[0] = m; P[1] = l;
#pragma unroll
  for (int d = 0; d < 32; ++d) P[2 + d] = o[d];
}

__global__ __launch_bounds__(256) void combine_k(const float* __restrict__ part,
                                                 float* __restrict__ attn_o) {
  int idx = blockIdx.x * 256 + threadIdx.x;  // over H*N
  if (idx >= HHD * NN) return;
  int h = idx >> 12, n = idx & (NN - 1);
  const float* P = part + (size_t)idx * KSPLIT * PART_STRIDE;
  float M = -1e30f;
#pragma unroll
  for (int z = 0; z < KSPLIT; ++z) M = fmaxf(M, P[z * PART_STRIDE]);
  float L = 0.f, o[32] = {};
#pragma unroll
  for (int z = 0; z < KSPLIT; ++z) {
    float w = __expf(P[z * PART_STRIDE] - M);
    L = fmaf(P[z * PART_STRIDE + 1], w, L);
#pragma unroll
    for (int d = 0; d < 32; ++d) o[d] = fmaf(P[z * PART_STRIDE + 2 + d], w, o[d]);
  }
  float inv = 1.f / L;
  float* op = attn_o + (size_t)n * DD + h * 32;
#pragma unroll
  for (int d = 0; d < 32; ++d) op[d] = o[d] * inv;
}

// ---------------- elementwise epilogues ----------------

__global__ __launch_bounds__(256) void ew_bn_res_k(float* __restrict__ io,
    const float* __restrict__ g, const float* __restrict__ b,
    const float* __restrict__ x, const float* __restrict__ extra) {
  int i = blockIdx.x * 256 + threadIdx.x;
  int d = i & 255;
  float s = g[d] * rsqrtf(1.0f + 1e-5f);
  float v = io[i] * s + b[d] + x[i];
  if (extra) v += extra[i];
  io[i] = v;
}

// ---------------- KAN ----------------

// Cox-de Boor, uniform grid g[j] = 0.5*j - 2.5 (11 knots), order 3 -> 7 bases.
template<int C>
__global__ __launch_bounds__(256) void bspl_c_k(const float* __restrict__ h,
                                                float* __restrict__ plane) {
  int i = blockIdx.x * 256 + threadIdx.x;  // < N*D
  float v = h[i];
  float b[10];
#pragma unroll
  for (int j = 0; j < 10; ++j) {
    float g0 = 0.5f * j - 2.5f;
    b[j] = (v >= g0 && v < g0 + 0.5f) ? 1.f : 0.f;
  }
#pragma unroll
  for (int kk = 1; kk <= 3; ++kk) {
    float inv = 2.f / (float)kk;
#pragma unroll
    for (int j = 0; j + kk < 10; ++j) {
      float g0 = 0.5f * j - 2.5f;
      float g1 = 0.5f * (j + kk + 1) - 2.5f;
      b[j] = (v - g0) * inv * b[j] + (g1 - v) * inv * b[j + 1];
    }
  }
  plane[i] = b[C];
}

// fwT[c][o][in] = spline[o][in][c] * scaler[o][in]
__global__ __launch_bounds__(256) void fuse_t_k(const float* __restrict__ sp,
    const float* __restrict__ sc, float* __restrict__ fwT) {
  int i = blockIdx.x * 256 + threadIdx.x;  // < D*D*7 ; layout (o, in, c)
  int o = i / (DD * COEF_);
  int rem = i - o * (DD * COEF_);
  int in = rem / COEF_;
  int c = rem - in * COEF_;
  fwT[(size_t)c * DD * DD + o * DD + in] = sp[i] * sc[o * DD + in];
}

// ---------------- launcher ----------------

extern "C" void kernel_launch(void* const* d_in, const int* in_sizes, int n_in,
                              void* d_out, int out_size, void* d_ws, size_t ws_size,
                              hipStream_t stream) {
  const float* x      = (const float*)d_in[0];
  const int* ei       = (const int*)d_in[1];
  const float* gcn_w1 = (const float*)d_in[2];
  const float* gcn_b1 = (const float*)d_in[3];
  const float* gcn_w2 = (const float*)d_in[4];
  const float* gcn_b2 = (const float*)d_in[5];
  const float* ln_g   = (const float*)d_in[6];
  const float* ln_b   = (const float*)d_in[7];
  const float* w_qkv  = (const float*)d_in[8];
  const float* b_qkv  = (const float*)d_in[9];
  const float* w_o    = (const float*)d_in[10];
  const float* b_o    = (const float*)d_in[11];
  const float* a_w1   = (const float*)d_in[12];
  const float* a_b1   = (const float*)d_in[13];
  const float* a_w2   = (const float*)d_in[14];
  const float* a_b2   = (const float*)d_in[15];
  const float* bn1_g  = (const float*)d_in[16];
  const float* bn1_b  = (const float*)d_in[17];
  const float* bn2_g  = (const float*)d_in[18];
  const float* bn2_b  = (const float*)d_in[19];
  const float* k1_base = (const float*)d_in[20];
  const float* k1_spl  = (const float*)d_in[21];
  const float* k1_scl  = (const float*)d_in[22];
  const float* k2_base = (const float*)d_in[23];
  const float* k2_spl  = (const float*)d_in[24];
  const float* k2_scl  = (const float*)d_in[25];

  float* outF = (float*)d_out;  // reference output dtype is float32

  const size_t ND = (size_t)NN * DD;              // 1,048,576
  const size_t PARTSZ = (size_t)HHD * NN * KSPLIT * PART_STRIDE;  // 2,228,224

  // Tight aliased workspace: ~10.6M floats = 42.5 MB total.
  float* ws = (float*)d_ws;
  float* dis      = ws;                    // [4096]
  float* buf_a    = dis + NN;              // [ND]  aggr -> attno -> spline plane
  float* buf_mid  = buf_a + ND;            // [2*ND] mid (GCN MLP, attn MLP)
  float* buf_xmfw = buf_mid + 2 * ND;      // [ND]  xm -> fwT (458752 < ND)
  float* buf_xnh1 = buf_xmfw + ND;         // [ND]  xn -> o-proj out -> h1
  float* buf_qkv  = buf_xnh1 + ND;         // [3*ND] qkv
  float* buf_ph   = buf_qkv + 3 * ND;      // [PARTSZ] part -> hbuf (ND < PARTSZ)

  float* aggr = buf_a;  float* attno = buf_a;  float* plane = buf_a;
  float* mid  = buf_mid;
  float* xm   = buf_xmfw; float* fwT = buf_xmfw;
  float* xn   = buf_xnh1; float* h1  = buf_xnh1;
  float* qkvb = buf_qkv;
  float* part = buf_ph;   float* hbuf = buf_ph;

  // ---- GCN aggregation ----
  hipMemsetAsync(dis, 0, NN * sizeof(float), stream);
  deg_k<<<EE / 256, 256, 0, stream>>>(ei, dis);
  dis_k<<<NN / 256, 256, 0, stream>>>(dis);
  selfinit_k<<<ND / 256, 256, 0, stream>>>(x, dis, aggr);
  scatter_k<<<EE / 4, 256, 0, stream>>>(ei, x, dis, aggr);
  // ---- GCN MLP + BN + residual ----
  gemm_nt<false, true, false><<<dim3(NN / 64, HIDN / 64), 256, 0, stream>>>(
      aggr, gcn_w1, gcn_b1, mid, NN, HIDN, DD);
  gemm_nt<false, false, false><<<dim3(NN / 64, DD / 64), 256, 0, stream>>>(
      mid, gcn_w2, gcn_b2, xm, NN, DD, HIDN);
  ew_bn_res_k<<<ND / 256, 256, 0, stream>>>(xm, bn1_g, bn1_b, x, nullptr);

  // ---- attention branch ----
  layernorm_k<<<NN, 256, 0, stream>>>(x, ln_g, ln_b, xn);
  gemm_nt<false, false, false><<<dim3(NN / 64, 768 / 64), 256, 0, stream>>>(
      xn, w_qkv, b_qkv, qkvb, NN, 3 * DD, DD);
  flash_k<<<dim3(NN / 64, HHD, KSPLIT), 64, 0, stream>>>(qkvb, part);
  combine_k<<<(HHD * NN) / 256, 256, 0, stream>>>(part, attno);
  gemm_nt<false, false, false><<<dim3(NN / 64, DD / 64), 256, 0, stream>>>(
      attno, w_o, b_o, xn, NN, DD, DD);   // xn now = o-proj out (LN xn dead)
  gemm_nt<false, true, false><<<dim3(NN / 64, HIDN / 64), 256, 0, stream>>>(
      xn, a_w1, a_b1, mid, NN, HIDN, DD);
  gemm_nt<false, false, false><<<dim3(NN / 64, DD / 64), 256, 0, stream>>>(
      mid, a_w2, a_b2, hbuf, NN, DD, HIDN);  // part dead -> hbuf
  ew_bn_res_k<<<ND / 256, 256, 0, stream>>>(hbuf, bn2_g, bn2_b, x, xm);  // hbuf = h

  // ---- KAN layer 1: h (hbuf) -> h1 ----
  fuse_t_k<<<(DD * DD * COEF_) / 256, 256, 0, stream>>>(k1_spl, k1_scl, fwT);  // xm dead
  gemm_nt<true, false, false><<<dim3(NN / 64, DD / 64), 256, 0, stream>>>(
      hbuf, k1_base, (const float*)nullptr, h1, NN, DD, DD);
#define KAN_SPLINE(SRC, DST)                                                     \
  {                                                                              \
    bspl_c_k<0><<<ND / 256, 256, 0, stream>>>(SRC, plane);                       \
    gemm_nt<false, false, true><<<dim3(NN / 64, DD / 64), 256, 0, stream>>>(     \
        plane, fwT + 0 * DD * DD, (const float*)nullptr, DST, NN, DD, DD);       \
    bspl_c_k<1><<<ND / 256, 256, 0, stream>>>(SRC, plane);                       \
    gemm_nt<false, false, true><<<dim3(NN / 64, DD / 64), 256, 0, stream>>>(     \
        plane, fwT + 1 * DD * DD, (const float*)nullptr, DST, NN, DD, DD);       \
    bspl_c_k<2><<<ND / 256, 256, 0, stream>>>(SRC, plane);                       \
    gemm_nt<false, false, true><<<dim3(NN / 64, DD / 64), 256, 0, stream>>>(     \
        plane, fwT + 2 * DD * DD, (const float*)nullptr, DST, NN, DD, DD);       \
    bspl_c_k<3><<<ND / 256, 256, 0, stream>>>(SRC, plane);                       \
    gemm_nt<false, false, true><<<dim3(NN / 64, DD / 64), 256, 0, stream>>>(     \
        plane, fwT + 3 * DD * DD, (const float*)nullptr, DST, NN, DD, DD);       \
    bspl_c_k<4><<<ND / 256, 256, 0, stream>>>(SRC, plane);                       \
    gemm_nt<false, false, true><<<dim3(NN / 64, DD / 64), 256, 0, stream>>>(     \
        plane, fwT + 4 * DD * DD, (const float*)nullptr, DST, NN, DD, DD);       \
    bspl_c_k<5><<<ND / 256, 256, 0, stream>>>(SRC, plane);                       \
    gemm_nt<false, false, true><<<dim3(NN / 64, DD / 64), 256, 0, stream>>>(     \
        plane, fwT + 5 * DD * DD, (const float*)nullptr, DST, NN, DD, DD);       \
    bspl_c_k<6><<<ND / 256, 256, 0, stream>>>(SRC, plane);                       \
    gemm_nt<false, false, true><<<dim3(NN / 64, DD / 64), 256, 0, stream>>>(     \
        plane, fwT + 6 * DD * DD, (const float*)nullptr, DST, NN, DD, DD);       \
  }
  KAN_SPLINE(hbuf, h1)

  // ---- KAN layer 2: h1 -> d_out (fp32) ----
  fuse_t_k<<<(DD * DD * COEF_) / 256, 256, 0, stream>>>(k2_spl, k2_scl, fwT);
  gemm_nt<true, false, false><<<dim3(NN / 64, DD / 64), 256, 0, stream>>>(
      h1, k2_base, (const float*)nullptr, outF, NN, DD, DD);
  KAN_SPLINE(h1, outF)
}

// Round 5
// 1289.680 us; speedup vs baseline: 1.4489x; 1.4489x over previous
//
#include <hip/hip_runtime.h>

typedef unsigned short u16;
typedef __attribute__((ext_vector_type(8))) short bf8;   // 8 bf16 in 4 VGPRs
typedef __attribute__((ext_vector_type(4))) float f32x4;

#define DEVINL __device__ __forceinline__

constexpr int NN = 4096, DD = 256, EE = 131072, HHD = 8, HIDN = 512, COEF_ = 7;

DEVINL u16 f2bf(float f) {
  union { float f; unsigned int i; } c; c.f = f;
  unsigned int u = c.i;
  return (u16)((u + 0x7FFFu + ((u >> 16) & 1u)) >> 16);
}
DEVINL unsigned pk2(float a, float b) {
  return (unsigned)f2bf(a) | ((unsigned)f2bf(b) << 16);
}
DEVINL float siluf(float x) { return x / (1.f + __expf(-x)); }

// ---------------- GCN graph part ----------------

__global__ void deg_k(const int* __restrict__ ei, float* __restrict__ deg) {
  int e = blockIdx.x * 256 + threadIdx.x;
  if (e < EE) atomicAdd(&deg[ei[e]], 1.0f);
}

__global__ void dis_k(float* __restrict__ deg) {
  int i = blockIdx.x * 256 + threadIdx.x;
  if (i < NN) deg[i] = rsqrtf(deg[i] + 1.0f);
}

__global__ __launch_bounds__(256) void selfinit_k(const float* __restrict__ x,
    const float* __restrict__ dis, float* __restrict__ aggr) {
  int i = blockIdx.x * 256 + threadIdx.x;
  int row = i >> 8;
  float dd = dis[row];
  aggr[i] = dd * dd * x[i];
}

__global__ __launch_bounds__(256) void scatter_k(const int* __restrict__ ei,
    const float* __restrict__ x, const float* __restrict__ dis, float* __restrict__ aggr) {
  int e = blockIdx.x * 4 + (threadIdx.x >> 6);
  if (e >= EE) return;
  int lane = threadIdx.x & 63;
  int s = ei[e], t = ei[EE + e];
  float nrm = dis[s] * dis[t];
  int d0 = lane * 4;
  const float4 xv = *(const float4*)(x + (size_t)s * DD + d0);
  float* ar = aggr + (size_t)t * DD + d0;
  atomicAdd(ar + 0, nrm * xv.x);
  atomicAdd(ar + 1, nrm * xv.y);
  atomicAdd(ar + 2, nrm * xv.z);
  atomicAdd(ar + 3, nrm * xv.w);
}

// ---------------- bf16 MFMA GEMM: C[n,m] = A[n,k] @ W[m,k]^T (+bias, epilogues) ----------------
// Tile 128x64, BK=64, 4 waves (2x2), per wave 64x32 = 4x2 fragments of 16x16x32.
// LDS XOR-swizzle: byte ^= (row&7)<<4 (breaks stride-128B bank conflict).

#define LSW(r, kb) ((((r) * 128 + ((kb) ^ (((r) & 7) << 4)))) >> 1)

template<bool SILU_A, bool SILU_OUT, bool ACCUM, bool A_BF16, bool W_SCALED>
__global__ __launch_bounds__(256) void mgemm(const void* __restrict__ Aptr,
    const float* __restrict__ W, const float* __restrict__ Wsc,
    const float* __restrict__ bias, float* __restrict__ C, int n, int m, int k)
{
  __shared__ u16 Al[128 * 64];  // 16 KB
  __shared__ u16 Wl[64 * 64];   // 8 KB
  const int tid = threadIdx.x;
  const int wid = tid >> 6, lane = tid & 63;
  const int wr = wid >> 1, wc = wid & 1;   // wave rows 64*wr, cols 32*wc
  const int bn = blockIdx.x * 128, bm = blockIdx.y * 64;
  const int ar = tid >> 1, ak0 = (tid & 1) * 32;   // A staging: row, k-start
  const int wrr = tid >> 2, wk0 = (tid & 3) * 16;  // W staging

  f32x4 acc[4][2] = {};

  for (int kt = 0; kt < k; kt += 64) {
    // ---- stage A tile (128 x 64) ----
    if (A_BF16) {
      const u16* Ap = (const u16*)Aptr + (size_t)(bn + ar) * k + kt + ak0;
#pragma unroll
      for (int c = 0; c < 4; ++c) {
        uint4 w = *(const uint4*)(Ap + 8 * c);
        *(uint4*)&Al[LSW(ar, 2 * ak0 + 16 * c)] = w;
      }
    } else {
      const float* Ap = (const float*)Aptr + (size_t)(bn + ar) * k + kt + ak0;
#pragma unroll
      for (int c = 0; c < 4; ++c) {
        float4 u = *(const float4*)(Ap + 8 * c);
        float4 v = *(const float4*)(Ap + 8 * c + 4);
        if (SILU_A) {
          u.x = siluf(u.x); u.y = siluf(u.y); u.z = siluf(u.z); u.w = siluf(u.w);
          v.x = siluf(v.x); v.y = siluf(v.y); v.z = siluf(v.z); v.w = siluf(v.w);
        }
        uint4 w;
        w.x = pk2(u.x, u.y); w.y = pk2(u.z, u.w);
        w.z = pk2(v.x, v.y); w.w = pk2(v.z, v.w);
        *(uint4*)&Al[LSW(ar, 2 * ak0 + 16 * c)] = w;
      }
    }
    // ---- stage W tile (64 x 64) ----
    {
      const float* Wp = W + (size_t)(bm + wrr) * k + kt + wk0;
#pragma unroll
      for (int c = 0; c < 2; ++c) {
        float fv[8];
        *(float4*)&fv[0] = *(const float4*)(Wp + 8 * c);
        *(float4*)&fv[4] = *(const float4*)(Wp + 8 * c + 4);
        if (W_SCALED) {
          const float* scrow = Wsc + (size_t)(bm + wrr) * 256;
#pragma unroll
          for (int j = 0; j < 8; ++j) {
            unsigned kidx = (unsigned)(kt + wk0 + 8 * c + j);
            fv[j] *= scrow[(kidx * 9363u) >> 16];   // kidx/7
          }
        }
        uint4 w;
        w.x = pk2(fv[0], fv[1]); w.y = pk2(fv[2], fv[3]);
        w.z = pk2(fv[4], fv[5]); w.w = pk2(fv[6], fv[7]);
        *(uint4*)&Wl[LSW(wrr, 2 * wk0 + 16 * c)] = w;
      }
    }
    __syncthreads();
    // ---- MFMA ----
#pragma unroll
    for (int kk = 0; kk < 64; kk += 32) {
      const int kb = (kk + (lane >> 4) * 8) * 2;
      bf8 av[4], bv[2];
#pragma unroll
      for (int fr = 0; fr < 4; ++fr) {
        int r = wr * 64 + fr * 16 + (lane & 15);
        av[fr] = *(const bf8*)&Al[LSW(r, kb)];
      }
#pragma unroll
      for (int fc = 0; fc < 2; ++fc) {
        int r = wc * 32 + fc * 16 + (lane & 15);
        bv[fc] = *(const bf8*)&Wl[LSW(r, kb)];
      }
#pragma unroll
      for (int fr = 0; fr < 4; ++fr)
#pragma unroll
        for (int fc = 0; fc < 2; ++fc)
          acc[fr][fc] = __builtin_amdgcn_mfma_f32_16x16x32_bf16(
              av[fr], bv[fc], acc[fr][fc], 0, 0, 0);
    }
    __syncthreads();
  }
  // ---- epilogue: D col = lane&15, row = (lane>>4)*4 + reg ----
#pragma unroll
  for (int fr = 0; fr < 4; ++fr)
#pragma unroll
    for (int fc = 0; fc < 2; ++fc) {
      int col = bm + wc * 32 + fc * 16 + (lane & 15);
      float bb = bias ? bias[col] : 0.f;
#pragma unroll
      for (int j = 0; j < 4; ++j) {
        int row = bn + wr * 64 + fr * 16 + (lane >> 4) * 4 + j;
        size_t idx = (size_t)row * m + col;
        float v = acc[fr][fc][j] + bb;
        if (ACCUM) v += C[idx];
        if (SILU_OUT) v = siluf(v);
        C[idx] = v;
      }
    }
}

// ---------------- LayerNorm ----------------

__global__ __launch_bounds__(256) void layernorm_k(const float* __restrict__ x,
    const float* __restrict__ g, const float* __restrict__ b, float* __restrict__ xn) {
  int row = blockIdx.x, t = threadIdx.x;
  float v = x[(size_t)row * DD + t];
  float s = v, sq = v * v;
#pragma unroll
  for (int o = 32; o > 0; o >>= 1) { s += __shfl_down(s, o); sq += __shfl_down(sq, o); }
  __shared__ float rs[4], rq[4];
  int wid = t >> 6, lane = t & 63;
  if (lane == 0) { rs[wid] = s; rq[wid] = sq; }
  __syncthreads();
  float S = rs[0] + rs[1] + rs[2] + rs[3];
  float SQ = rq[0] + rq[1] + rq[2] + rq[3];
  float mu = S * (1.f / 256.f);
  float var = SQ * (1.f / 256.f) - mu * mu;
  float inv = rsqrtf(var + 1e-5f);
  xn[(size_t)row * DD + t] = (v - mu) * inv * g[t] + b[t];
}

// ---------------- flash attention v2: 4 waves/block, per-wave KV split, in-block combine ----

__global__ __launch_bounds__(256) void flash2(const float* __restrict__ qkv,
                                              float* __restrict__ attno) {
  const int h = blockIdx.y, qb = blockIdx.x;
  const int tid = threadIdx.x, wid = tid >> 6, lane = tid & 63;
  const int n = qb * 64 + lane;
  __shared__ float Ks[4][64][36];
  __shared__ float Vs[4][64][36];
  const float* qr = qkv + (size_t)n * 768 + h * 32;
  float q[32];
#pragma unroll
  for (int d = 0; d < 32; d += 4) {
    float4 t4 = *(const float4*)&qr[d];
    q[d] = t4.x; q[d + 1] = t4.y; q[d + 2] = t4.z; q[d + 3] = t4.w;
  }
  float m = -1e30f, l = 0.f, o[32] = {};
  const int kb0 = wid * (NN / 4);
  for (int t = 0; t < NN / 4; t += 64) {
    __syncthreads();
    const float* kr = qkv + (size_t)(kb0 + t + lane) * 768 + 256 + h * 32;
    const float* vr = kr + 256;
#pragma unroll
    for (int d = 0; d < 32; d += 4) {
      *(float4*)&Ks[wid][lane][d] = *(const float4*)&kr[d];
      *(float4*)&Vs[wid][lane][d] = *(const float4*)&vr[d];
    }
    __syncthreads();
    for (int j = 0; j < 64; ++j) {
      float s = 0.f;
#pragma unroll
      for (int d = 0; d < 32; d += 4) {
        float4 kk4 = *(const float4*)&Ks[wid][j][d];
        s = fmaf(q[d], kk4.x, s); s = fmaf(q[d + 1], kk4.y, s);
        s = fmaf(q[d + 2], kk4.z, s); s = fmaf(q[d + 3], kk4.w, s);
      }
      s *= 0.17677669529663687f;  // 1/sqrt(32)
      if (s > m) {
        float c = __expf(m - s);
        m = s;
        l = fmaf(l, c, 1.f);
#pragma unroll
        for (int d = 0; d < 32; d += 4) {
          float4 vv = *(const float4*)&Vs[wid][j][d];
          o[d] = fmaf(o[d], c, vv.x); o[d + 1] = fmaf(o[d + 1], c, vv.y);
          o[d + 2] = fmaf(o[d + 2], c, vv.z); o[d + 3] = fmaf(o[d + 3], c, vv.w);
        }
      } else {
        float p = __expf(s - m);
        l += p;
#pragma unroll
        for (int d = 0; d < 32; d += 4) {
          float4 vv = *(const float4*)&Vs[wid][j][d];
          o[d] = fmaf(p, vv.x, o[d]); o[d + 1] = fmaf(p, vv.y, o[d + 1]);
          o[d + 2] = fmaf(p, vv.z, o[d + 2]); o[d + 3] = fmaf(p, vv.w, o[d + 3]);
        }
      }
    }
  }
  // write partials to LDS (reuse Ks: 9216 floats >= 4*64*34)
  __syncthreads();
  float* P = (float*)Ks + ((size_t)(wid * 64 + lane) * 34);
  P[0] = m; P[1] = l;
#pragma unroll
  for (int d = 0; d < 32; ++d) P[2 + d] = o[d];
  __syncthreads();
  if (wid == 0) {
    float M = -1e30f;
#pragma unroll
    for (int z = 0; z < 4; ++z) M = fmaxf(M, ((float*)Ks)[(z * 64 + lane) * 34]);
    float L = 0.f, oo[32] = {};
#pragma unroll
    for (int z = 0; z < 4; ++z) {
      const float* Pz = (float*)Ks + ((size_t)(z * 64 + lane) * 34);
      float w = __expf(Pz[0] - M);
      L = fmaf(Pz[1], w, L);
#pragma unroll
      for (int d = 0; d < 32; ++d) oo[d] = fmaf(Pz[2 + d], w, oo[d]);
    }
    float inv = 1.f / L;
    float* op = attno + (size_t)n * DD + h * 32;
#pragma unroll
    for (int d = 0; d < 32; d += 4) {
      float4 w4 = { oo[d] * inv, oo[d + 1] * inv, oo[d + 2] * inv, oo[d + 3] * inv };
      *(float4*)&op[d] = w4;
    }
  }
}

// ---------------- elementwise epilogues ----------------

__global__ __launch_bounds__(256) void ew_bn_res_k(float* __restrict__ io,
    const float* __restrict__ g, const float* __restrict__ b,
    const float* __restrict__ x, const float* __restrict__ extra) {
  int i = blockIdx.x * 256 + threadIdx.x;
  int d = i & 255;
  float s = g[d] * rsqrtf(1.0f + 1e-5f);
  float v = io[i] * s + b[d] + x[i];
  if (extra) v += extra[i];
  io[i] = v;
}

// ---------------- KAN: all 7 spline bases -> bf16 [N, D*7] ----------------

__global__ __launch_bounds__(256) void bspl_all_k(const float* __restrict__ h,
                                                  u16* __restrict__ bases) {
  int i = blockIdx.x * 256 + threadIdx.x;  // < N*D
  float v = h[i];
  float b[10];
#pragma unroll
  for (int j = 0; j < 10; ++j) {
    float g0 = 0.5f * j - 2.5f;
    b[j] = (v >= g0 && v < g0 + 0.5f) ? 1.f : 0.f;
  }
#pragma unroll
  for (int kk = 1; kk <= 3; ++kk) {
    float inv = 2.f / (float)kk;
#pragma unroll
    for (int j = 0; j + kk < 10; ++j) {
      float g0 = 0.5f * j - 2.5f;
      float g1 = 0.5f * (j + kk + 1) - 2.5f;
      b[j] = (v - g0) * inv * b[j] + (g1 - v) * inv * b[j + 1];
    }
  }
  u16* o = bases + (size_t)i * 7;
#pragma unroll
  for (int c = 0; c < 7; ++c) o[c] = f2bf(b[c]);
}

// ---------------- launcher ----------------

extern "C" void kernel_launch(void* const* d_in, const int* in_sizes, int n_in,
                              void* d_out, int out_size, void* d_ws, size_t ws_size,
                              hipStream_t stream) {
  const float* x      = (const float*)d_in[0];
  const int* ei       = (const int*)d_in[1];
  const float* gcn_w1 = (const float*)d_in[2];
  const float* gcn_b1 = (const float*)d_in[3];
  const float* gcn_w2 = (const float*)d_in[4];
  const float* gcn_b2 = (const float*)d_in[5];
  const float* ln_g   = (const float*)d_in[6];
  const float* ln_b   = (const float*)d_in[7];
  const float* w_qkv  = (const float*)d_in[8];
  const float* b_qkv  = (const float*)d_in[9];
  const float* w_o    = (const float*)d_in[10];
  const float* b_o    = (const float*)d_in[11];
  const float* a_w1   = (const float*)d_in[12];
  const float* a_b1   = (const float*)d_in[13];
  const float* a_w2   = (const float*)d_in[14];
  const float* a_b2   = (const float*)d_in[15];
  const float* bn1_g  = (const float*)d_in[16];
  const float* bn1_b  = (const float*)d_in[17];
  const float* bn2_g  = (const float*)d_in[18];
  const float* bn2_b  = (const float*)d_in[19];
  const float* k1_base = (const float*)d_in[20];
  const float* k1_spl  = (const float*)d_in[21];
  const float* k1_scl  = (const float*)d_in[22];
  const float* k2_base = (const float*)d_in[23];
  const float* k2_spl  = (const float*)d_in[24];
  const float* k2_scl  = (const float*)d_in[25];

  float* outF = (float*)d_out;

  const size_t ND = (size_t)NN * DD;            // 1,048,576
  const size_t BASES_F = 3670016;               // N*D*7 u16 as floats

  // Aliased workspace: 39.9 MB
  float* ws = (float*)d_ws;
  float* dis  = ws;                   // [4096]
  float* R1   = dis + NN;             // [ND]       aggr -> attno
  float* R5   = R1 + ND;              // [N*512]    mid
  float* R4   = R5 + (size_t)NN * HIDN; // [ND]     xm
  float* R2   = R4 + ND;              // [ND]       xn -> o-out -> h1
  float* R3   = R2 + ND;              // [3.67M]    qkv -> bases(u16)
  float* R6   = R3 + BASES_F;         // [ND]       hbuf

  float* aggr = R1; float* attno = R1;
  float* mid  = R5;
  float* xm   = R4;
  float* xn   = R2; float* h1 = R2;
  float* qkvb = R3; u16* bases = (u16*)R3;
  float* hbuf = R6;

  const dim3 B256(256);

  // ---- GCN aggregation ----
  hipMemsetAsync(dis, 0, NN * sizeof(float), stream);
  deg_k<<<EE / 256, B256, 0, stream>>>(ei, dis);
  dis_k<<<NN / 256, B256, 0, stream>>>(dis);
  selfinit_k<<<ND / 256, B256, 0, stream>>>(x, dis, aggr);
  scatter_k<<<EE / 4, B256, 0, stream>>>(ei, x, dis, aggr);
  // ---- GCN MLP + BN + residual ----
  mgemm<false, true, false, false, false><<<dim3(32, HIDN / 64), B256, 0, stream>>>(
      aggr, gcn_w1, nullptr, gcn_b1, mid, NN, HIDN, DD);
  mgemm<false, false, false, false, false><<<dim3(32, DD / 64), B256, 0, stream>>>(
      mid, gcn_w2, nullptr, gcn_b2, xm, NN, DD, HIDN);
  ew_bn_res_k<<<ND / 256, B256, 0, stream>>>(xm, bn1_g, bn1_b, x, nullptr);

  // ---- attention branch ----
  layernorm_k<<<NN, B256, 0, stream>>>(x, ln_g, ln_b, xn);
  mgemm<false, false, false, false, false><<<dim3(32, 768 / 64), B256, 0, stream>>>(
      xn, w_qkv, nullptr, b_qkv, qkvb, NN, 3 * DD, DD);
  flash2<<<dim3(NN / 64, HHD), B256, 0, stream>>>(qkvb, attno);
  mgemm<false, false, false, false, false><<<dim3(32, DD / 64), B256, 0, stream>>>(
      attno, w_o, nullptr, b_o, xn, NN, DD, DD);
  mgemm<false, true, false, false, false><<<dim3(32, HIDN / 64), B256, 0, stream>>>(
      xn, a_w1, nullptr, a_b1, mid, NN, HIDN, DD);
  mgemm<false, false, false, false, false><<<dim3(32, DD / 64), B256, 0, stream>>>(
      mid, a_w2, nullptr, a_b2, hbuf, NN, DD, HIDN);
  ew_bn_res_k<<<ND / 256, B256, 0, stream>>>(hbuf, bn2_g, bn2_b, x, xm);  // hbuf = h

  // ---- KAN layer 1: h (hbuf) -> h1 ----
  bspl_all_k<<<ND / 256, B256, 0, stream>>>(hbuf, bases);
  mgemm<true, false, false, false, false><<<dim3(32, DD / 64), B256, 0, stream>>>(
      hbuf, k1_base, nullptr, nullptr, h1, NN, DD, DD);
  mgemm<false, false, true, true, true><<<dim3(32, DD / 64), B256, 0, stream>>>(
      bases, k1_spl, k1_scl, nullptr, h1, NN, DD, DD * COEF_);

  // ---- KAN layer 2: h1 -> d_out ----
  bspl_all_k<<<ND / 256, B256, 0, stream>>>(h1, bases);
  mgemm<true, false, false, false, false><<<dim3(32, DD / 64), B256, 0, stream>>>(
      h1, k2_base, nullptr, nullptr, outF, NN, DD, DD);
  mgemm<false, false, true, true, true><<<dim3(32, DD / 64), B256, 0, stream>>>(
      bases, k2_spl, k2_scl, nullptr, outF, NN, DD, DD * COEF_);
}

// Round 6
// 986.600 us; speedup vs baseline: 1.8941x; 1.3072x over previous
//
#include <hip/hip_runtime.h>

typedef unsigned short u16;
typedef __attribute__((ext_vector_type(8))) short bf8;   // 8 bf16 in 4 VGPRs
typedef __attribute__((ext_vector_type(4))) float f32x4;

#define DEVINL __device__ __forceinline__

constexpr int NN = 4096, DD = 256, EE = 131072, HHD = 8, HIDN = 512, COEF_ = 7;

DEVINL u16 f2bf(float f) {
  union { float f; unsigned int i; } c; c.f = f;
  unsigned int u = c.i;
  return (u16)((u + 0x7FFFu + ((u >> 16) & 1u)) >> 16);
}
DEVINL unsigned pk2(float a, float b) {
  return (unsigned)f2bf(a) | ((unsigned)f2bf(b) << 16);
}
DEVINL float siluf(float x) { return x / (1.f + __expf(-x)); }

// ---------------- GCN graph part ----------------

__global__ void deg_k(const int* __restrict__ ei, float* __restrict__ deg) {
  int e = blockIdx.x * 256 + threadIdx.x;
  if (e < EE) atomicAdd(&deg[ei[e]], 1.0f);
}

__global__ void dis_k(float* __restrict__ deg) {
  int i = blockIdx.x * 256 + threadIdx.x;
  if (i < NN) deg[i] = rsqrtf(deg[i] + 1.0f);
}

__global__ __launch_bounds__(256) void selfinit_k(const float* __restrict__ x,
    const float* __restrict__ dis, float* __restrict__ aggr) {
  int i = blockIdx.x * 256 + threadIdx.x;
  int row = i >> 8;
  float dd = dis[row];
  aggr[i] = dd * dd * x[i];
}

__global__ __launch_bounds__(256) void scatter_k(const int* __restrict__ ei,
    const float* __restrict__ x, const float* __restrict__ dis, float* __restrict__ aggr) {
  int e = blockIdx.x * 4 + (threadIdx.x >> 6);
  if (e >= EE) return;
  int lane = threadIdx.x & 63;
  int s = ei[e], t = ei[EE + e];
  float nrm = dis[s] * dis[t];
  int d0 = lane * 4;
  const float4 xv = *(const float4*)(x + (size_t)s * DD + d0);
  float* ar = aggr + (size_t)t * DD + d0;
  atomicAdd(ar + 0, nrm * xv.x);
  atomicAdd(ar + 1, nrm * xv.y);
  atomicAdd(ar + 2, nrm * xv.z);
  atomicAdd(ar + 3, nrm * xv.w);
}

// ---------------- bf16 MFMA GEMM: C[n,m] = A[n,k] @ W[m,k]^T ----------------

#define LSW(r, kb) ((((r) * 128 + ((kb) ^ (((r) & 7) << 4)))) >> 1)

template<bool SILU_A, bool SILU_OUT, bool ACCUM, bool A_BF16, bool W_SCALED>
__global__ __launch_bounds__(256) void mgemm(const void* __restrict__ Aptr,
    const float* __restrict__ W, const float* __restrict__ Wsc,
    const float* __restrict__ bias, float* __restrict__ C, int n, int m, int k)
{
  __shared__ u16 Al[128 * 64];
  __shared__ u16 Wl[64 * 64];
  const int tid = threadIdx.x;
  const int wid = tid >> 6, lane = tid & 63;
  const int wr = wid >> 1, wc = wid & 1;
  const int bn = blockIdx.x * 128, bm = blockIdx.y * 64;
  const int ar = tid >> 1, ak0 = (tid & 1) * 32;
  const int wrr = tid >> 2, wk0 = (tid & 3) * 16;

  f32x4 acc[4][2] = {};

  for (int kt = 0; kt < k; kt += 64) {
    if (A_BF16) {
      const u16* Ap = (const u16*)Aptr + (size_t)(bn + ar) * k + kt + ak0;
#pragma unroll
      for (int c = 0; c < 4; ++c) {
        uint4 w = *(const uint4*)(Ap + 8 * c);
        *(uint4*)&Al[LSW(ar, 2 * ak0 + 16 * c)] = w;
      }
    } else {
      const float* Ap = (const float*)Aptr + (size_t)(bn + ar) * k + kt + ak0;
#pragma unroll
      for (int c = 0; c < 4; ++c) {
        float4 u = *(const float4*)(Ap + 8 * c);
        float4 v = *(const float4*)(Ap + 8 * c + 4);
        if (SILU_A) {
          u.x = siluf(u.x); u.y = siluf(u.y); u.z = siluf(u.z); u.w = siluf(u.w);
          v.x = siluf(v.x); v.y = siluf(v.y); v.z = siluf(v.z); v.w = siluf(v.w);
        }
        uint4 w;
        w.x = pk2(u.x, u.y); w.y = pk2(u.z, u.w);
        w.z = pk2(v.x, v.y); w.w = pk2(v.z, v.w);
        *(uint4*)&Al[LSW(ar, 2 * ak0 + 16 * c)] = w;
      }
    }
    {
      const float* Wp = W + (size_t)(bm + wrr) * k + kt + wk0;
#pragma unroll
      for (int c = 0; c < 2; ++c) {
        float fv[8];
        *(float4*)&fv[0] = *(const float4*)(Wp + 8 * c);
        *(float4*)&fv[4] = *(const float4*)(Wp + 8 * c + 4);
        if (W_SCALED) {
          const float* scrow = Wsc + (size_t)(bm + wrr) * 256;
#pragma unroll
          for (int j = 0; j < 8; ++j) {
            unsigned kidx = (unsigned)(kt + wk0 + 8 * c + j);
            fv[j] *= scrow[(kidx * 9363u) >> 16];
          }
        }
        uint4 w;
        w.x = pk2(fv[0], fv[1]); w.y = pk2(fv[2], fv[3]);
        w.z = pk2(fv[4], fv[5]); w.w = pk2(fv[6], fv[7]);
        *(uint4*)&Wl[LSW(wrr, 2 * wk0 + 16 * c)] = w;
      }
    }
    __syncthreads();
#pragma unroll
    for (int kk = 0; kk < 64; kk += 32) {
      const int kb = (kk + (lane >> 4) * 8) * 2;
      bf8 av[4], bv[2];
#pragma unroll
      for (int fr = 0; fr < 4; ++fr) {
        int r = wr * 64 + fr * 16 + (lane & 15);
        av[fr] = *(const bf8*)&Al[LSW(r, kb)];
      }
#pragma unroll
      for (int fc = 0; fc < 2; ++fc) {
        int r = wc * 32 + fc * 16 + (lane & 15);
        bv[fc] = *(const bf8*)&Wl[LSW(r, kb)];
      }
#pragma unroll
      for (int fr = 0; fr < 4; ++fr)
#pragma unroll
        for (int fc = 0; fc < 2; ++fc)
          acc[fr][fc] = __builtin_amdgcn_mfma_f32_16x16x32_bf16(
              av[fr], bv[fc], acc[fr][fc], 0, 0, 0);
    }
    __syncthreads();
  }
#pragma unroll
  for (int fr = 0; fr < 4; ++fr)
#pragma unroll
    for (int fc = 0; fc < 2; ++fc) {
      int col = bm + wc * 32 + fc * 16 + (lane & 15);
      float bb = bias ? bias[col] : 0.f;
#pragma unroll
      for (int j = 0; j < 4; ++j) {
        int row = bn + wr * 64 + fr * 16 + (lane >> 4) * 4 + j;
        size_t idx = (size_t)row * m + col;
        float v = acc[fr][fc][j] + bb;
        if (ACCUM) v += C[idx];
        if (SILU_OUT) v = siluf(v);
        C[idx] = v;
      }
    }
}

// ---------------- LayerNorm ----------------

__global__ __launch_bounds__(256) void layernorm_k(const float* __restrict__ x,
    const float* __restrict__ g, const float* __restrict__ b, float* __restrict__ xn) {
  int row = blockIdx.x, t = threadIdx.x;
  float v = x[(size_t)row * DD + t];
  float s = v, sq = v * v;
#pragma unroll
  for (int o = 32; o > 0; o >>= 1) { s += __shfl_down(s, o); sq += __shfl_down(sq, o); }
  __shared__ float rs[4], rq[4];
  int wid = t >> 6, lane = t & 63;
  if (lane == 0) { rs[wid] = s; rq[wid] = sq; }
  __syncthreads();
  float S = rs[0] + rs[1] + rs[2] + rs[3];
  float SQ = rq[0] + rq[1] + rq[2] + rq[3];
  float mu = S * (1.f / 256.f);
  float var = SQ * (1.f / 256.f) - mu * mu;
  float inv = rsqrtf(var + 1e-5f);
  xn[(size_t)row * DD + t] = (v - mu) * inv * g[t] + b[t];
}

// ---------------- QKV fp32 -> bf16 (q-columns pre-scaled into exp2 domain) ----------------

__global__ __launch_bounds__(256) void cvtqkv_k(const float* __restrict__ in,
                                                u16* __restrict__ out) {
  int i = blockIdx.x * 256 + threadIdx.x;  // < N*768
  int col = i % 768;
  float v = in[i];
  if (col < 256) v *= 0.25500526764f;  // (1/sqrt(32)) * log2(e)
  out[i] = f2bf(v);
}

// ---------------- MFMA flash attention: no barriers, per-wave 16 q-rows ----------------
// S^T = mfma(K_frag, Q_frag) -> lane&15 = q. Softmax lane-local + shfl_xor(16,32).
// P redistributed via per-wave LDS fragment buffer; O = mfma(P_frag, V_frag).

__global__ __launch_bounds__(256) void flash3(const u16* __restrict__ qkv16,
                                              float* __restrict__ attno) {
  const int h = blockIdx.y, qb = blockIdx.x;
  const int tid = threadIdx.x, wid = tid >> 6;
  const int l15 = tid & 15, hi = (tid >> 4) & 3;
  __shared__ u16 Pf[4][2][64][8];  // [wave][k-step][lane-slot][elem] = 8 KB

  const bf8 qf = *(const bf8*)(qkv16 +
      (size_t)(qb * 64 + wid * 16 + l15) * 768 + h * 32 + hi * 8);

  float m = -3.0e38f, l = 0.f;
  f32x4 oa0 = {}, oa1 = {};

  for (int t = 0; t < NN; t += 64) {
    // ---- K A-frags + QK^T ----
    f32x4 sc[4];
    const u16* kbase = qkv16 + (size_t)t * 768 + 256 + h * 32 + hi * 8;
#pragma unroll
    for (int f = 0; f < 4; ++f) {
      bf8 kf = *(const bf8*)(kbase + (size_t)(f * 16 + l15) * 768);
      f32x4 z = {};
      sc[f] = __builtin_amdgcn_mfma_f32_16x16x32_bf16(kf, qf, z, 0, 0, 0);
    }
    // ---- V B-frag gathers (issued early; latency hides under softmax) ----
    bf8 vf[2][2];
    const u16* vbase = qkv16 + (size_t)t * 768 + 512 + h * 32;
#pragma unroll
    for (int s = 0; s < 2; ++s)
#pragma unroll
      for (int a = 0; a < 2; ++a) {
        const u16* vp = vbase + (size_t)(s * 32 + hi * 8) * 768 + a * 16 + l15;
#pragma unroll
        for (int i = 0; i < 8; ++i) vf[s][a][i] = (short)vp[(size_t)i * 768];
      }
    // ---- online softmax over q = l15 ----
    float mx = sc[0][0];
#pragma unroll
    for (int f = 0; f < 4; ++f)
#pragma unroll
      for (int j = 0; j < 4; ++j) mx = fmaxf(mx, sc[f][j]);
    mx = fmaxf(mx, __shfl_xor(mx, 16));
    mx = fmaxf(mx, __shfl_xor(mx, 32));
    float mn = fmaxf(m, mx);
    float scale = exp2f(m - mn);
    m = mn;
    float sum = 0.f;
#pragma unroll
    for (int f = 0; f < 4; ++f)
#pragma unroll
      for (int j = 0; j < 4; ++j) { sc[f][j] = exp2f(sc[f][j] - mn); sum += sc[f][j]; }
    sum += __shfl_xor(sum, 16);
    sum += __shfl_xor(sum, 32);
    l = l * scale + sum;
    // rescale O accs (acc rows q' = hi*4+j)
#pragma unroll
    for (int j = 0; j < 4; ++j) {
      float scj = __shfl(scale, hi * 4 + j);
      oa0[j] *= scj; oa1[j] *= scj;
    }
    // ---- pack P into per-wave LDS fragment layout ----
#pragma unroll
    for (int f = 0; f < 4; ++f) {
      unsigned lo, hi2;
      asm("v_cvt_pk_bf16_f32 %0, %1, %2" : "=v"(lo) : "v"(sc[f][0]), "v"(sc[f][1]));
      asm("v_cvt_pk_bf16_f32 %0, %1, %2" : "=v"(hi2) : "v"(sc[f][2]), "v"(sc[f][3]));
      uint2 pr; pr.x = lo; pr.y = hi2;
      *(uint2*)&Pf[wid][f >> 1][l15 | (((f * 2 + (hi >> 1)) & 3) << 4)][(hi & 1) * 4] = pr;
    }
    // ---- PV ----
#pragma unroll
    for (int s = 0; s < 2; ++s) {
      bf8 pa = *(const bf8*)&Pf[wid][s][l15 | (hi << 4)][0];
      oa0 = __builtin_amdgcn_mfma_f32_16x16x32_bf16(pa, vf[s][0], oa0, 0, 0, 0);
      oa1 = __builtin_amdgcn_mfma_f32_16x16x32_bf16(pa, vf[s][1], oa1, 0, 0, 0);
    }
  }
  // ---- epilogue: lane holds O[q=hi*4+j][d=a*16+l15] ----
#pragma unroll
  for (int j = 0; j < 4; ++j) {
    float lj = __shfl(l, hi * 4 + j);
    float inv = 1.f / lj;
    int q = qb * 64 + wid * 16 + hi * 4 + j;
    attno[(size_t)q * DD + h * 32 + l15] = oa0[j] * inv;
    attno[(size_t)q * DD + h * 32 + 16 + l15] = oa1[j] * inv;
  }
}

// ---------------- elementwise epilogues ----------------

__global__ __launch_bounds__(256) void ew_bn_res_k(float* __restrict__ io,
    const float* __restrict__ g, const float* __restrict__ b,
    const float* __restrict__ x, const float* __restrict__ extra) {
  int i = blockIdx.x * 256 + threadIdx.x;
  int d = i & 255;
  float s = g[d] * rsqrtf(1.0f + 1e-5f);
  float v = io[i] * s + b[d] + x[i];
  if (extra) v += extra[i];
  io[i] = v;
}

// ---------------- KAN: all 7 spline bases -> bf16 [N, D*7] ----------------

__global__ __launch_bounds__(256) void bspl_all_k(const float* __restrict__ h,
                                                  u16* __restrict__ bases) {
  int i = blockIdx.x * 256 + threadIdx.x;
  float v = h[i];
  float b[10];
#pragma unroll
  for (int j = 0; j < 10; ++j) {
    float g0 = 0.5f * j - 2.5f;
    b[j] = (v >= g0 && v < g0 + 0.5f) ? 1.f : 0.f;
  }
#pragma unroll
  for (int kk = 1; kk <= 3; ++kk) {
    float inv = 2.f / (float)kk;
#pragma unroll
    for (int j = 0; j + kk < 10; ++j) {
      float g0 = 0.5f * j - 2.5f;
      float g1 = 0.5f * (j + kk + 1) - 2.5f;
      b[j] = (v - g0) * inv * b[j] + (g1 - v) * inv * b[j + 1];
    }
  }
  u16* o = bases + (size_t)i * 7;
#pragma unroll
  for (int c = 0; c < 7; ++c) o[c] = f2bf(b[c]);
}

// ---------------- launcher ----------------

extern "C" void kernel_launch(void* const* d_in, const int* in_sizes, int n_in,
                              void* d_out, int out_size, void* d_ws, size_t ws_size,
                              hipStream_t stream) {
  const float* x      = (const float*)d_in[0];
  const int* ei       = (const int*)d_in[1];
  const float* gcn_w1 = (const float*)d_in[2];
  const float* gcn_b1 = (const float*)d_in[3];
  const float* gcn_w2 = (const float*)d_in[4];
  const float* gcn_b2 = (const float*)d_in[5];
  const float* ln_g   = (const float*)d_in[6];
  const float* ln_b   = (const float*)d_in[7];
  const float* w_qkv  = (const float*)d_in[8];
  const float* b_qkv  = (const float*)d_in[9];
  const float* w_o    = (const float*)d_in[10];
  const float* b_o    = (const float*)d_in[11];
  const float* a_w1   = (const float*)d_in[12];
  const float* a_b1   = (const float*)d_in[13];
  const float* a_w2   = (const float*)d_in[14];
  const float* a_b2   = (const float*)d_in[15];
  const float* bn1_g  = (const float*)d_in[16];
  const float* bn1_b  = (const float*)d_in[17];
  const float* bn2_g  = (const float*)d_in[18];
  const float* bn2_b  = (const float*)d_in[19];
  const float* k1_base = (const float*)d_in[20];
  const float* k1_spl  = (const float*)d_in[21];
  const float* k1_scl  = (const float*)d_in[22];
  const float* k2_base = (const float*)d_in[23];
  const float* k2_spl  = (const float*)d_in[24];
  const float* k2_scl  = (const float*)d_in[25];

  float* outF = (float*)d_out;

  const size_t ND = (size_t)NN * DD;
  const size_t BASES_F = 3670016;

  float* ws = (float*)d_ws;
  float* dis  = ws;                     // [4096]
  float* R1   = dis + NN;               // [ND]     aggr -> attno
  float* R5   = R1 + ND;                // [2*ND]   mid; qkv-bf16 during attn window
  float* R4   = R5 + (size_t)NN * HIDN; // [ND]     xm
  float* R2   = R4 + ND;                // [ND]     xn -> o-out -> h1
  float* R3   = R2 + ND;                // [3.67M]  qkv fp32 -> bases(u16)
  float* R6   = R3 + BASES_F;           // [ND]     hbuf

  float* aggr = R1; float* attno = R1;
  float* mid  = R5; u16* qkv16 = (u16*)R5;  // mid free between GCN MLP and a_w1
  float* xm   = R4;
  float* xn   = R2; float* h1 = R2;
  float* qkvb = R3; u16* bases = (u16*)R3;
  float* hbuf = R6;

  const dim3 B256(256);

  // ---- GCN aggregation ----
  hipMemsetAsync(dis, 0, NN * sizeof(float), stream);
  deg_k<<<EE / 256, B256, 0, stream>>>(ei, dis);
  dis_k<<<NN / 256, B256, 0, stream>>>(dis);
  selfinit_k<<<ND / 256, B256, 0, stream>>>(x, dis, aggr);
  scatter_k<<<EE / 4, B256, 0, stream>>>(ei, x, dis, aggr);
  // ---- GCN MLP + BN + residual ----
  mgemm<false, true, false, false, false><<<dim3(32, HIDN / 64), B256, 0, stream>>>(
      aggr, gcn_w1, nullptr, gcn_b1, mid, NN, HIDN, DD);
  mgemm<false, false, false, false, false><<<dim3(32, DD / 64), B256, 0, stream>>>(
      mid, gcn_w2, nullptr, gcn_b2, xm, NN, DD, HIDN);
  ew_bn_res_k<<<ND / 256, B256, 0, stream>>>(xm, bn1_g, bn1_b, x, nullptr);

  // ---- attention branch ----
  layernorm_k<<<NN, B256, 0, stream>>>(x, ln_g, ln_b, xn);
  mgemm<false, false, false, false, false><<<dim3(32, 768 / 64), B256, 0, stream>>>(
      xn, w_qkv, nullptr, b_qkv, qkvb, NN, 3 * DD, DD);
  cvtqkv_k<<<(NN * 768) / 256, B256, 0, stream>>>(qkvb, qkv16);
  flash3<<<dim3(NN / 64, HHD), B256, 0, stream>>>(qkv16, attno);
  mgemm<false, false, false, false, false><<<dim3(32, DD / 64), B256, 0, stream>>>(
      attno, w_o, nullptr, b_o, xn, NN, DD, DD);
  mgemm<false, true, false, false, false><<<dim3(32, HIDN / 64), B256, 0, stream>>>(
      xn, a_w1, nullptr, a_b1, mid, NN, HIDN, DD);
  mgemm<false, false, false, false, false><<<dim3(32, DD / 64), B256, 0, stream>>>(
      mid, a_w2, nullptr, a_b2, hbuf, NN, DD, HIDN);
  ew_bn_res_k<<<ND / 256, B256, 0, stream>>>(hbuf, bn2_g, bn2_b, x, xm);  // hbuf = h

  // ---- KAN layer 1: h (hbuf) -> h1 ----
  bspl_all_k<<<ND / 256, B256, 0, stream>>>(hbuf, bases);
  mgemm<true, false, false, false, false><<<dim3(32, DD / 64), B256, 0, stream>>>(
      hbuf, k1_base, nullptr, nullptr, h1, NN, DD, DD);
  mgemm<false, false, true, true, true><<<dim3(32, DD / 64), B256, 0, stream>>>(
      bases, k1_spl, k1_scl, nullptr, h1, NN, DD, DD * COEF_);

  // ---- KAN layer 2: h1 -> d_out ----
  bspl_all_k<<<ND / 256, B256, 0, stream>>>(h1, bases);
  mgemm<true, false, false, false, false><<<dim3(32, DD / 64), B256, 0, stream>>>(
      h1, k2_base, nullptr, nullptr, outF, NN, DD, DD);
  mgemm<false, false, true, true, true><<<dim3(32, DD / 64), B256, 0, stream>>>(
      bases, k2_spl, k2_scl, nullptr, outF, NN, DD, DD * COEF_);
}

// Round 7
// 601.079 us; speedup vs baseline: 3.1089x; 1.6414x over previous
//
#include <hip/hip_runtime.h>

typedef unsigned short u16;
typedef __attribute__((ext_vector_type(8))) short bf8;   // 8 bf16 in 4 VGPRs
typedef __attribute__((ext_vector_type(4))) float f32x4;

#define DEVINL __device__ __forceinline__

constexpr int NN = 4096, DD = 256, EE = 131072, HHD = 8, HIDN = 512, COEF_ = 7;

DEVINL u16 f2bf(float f) {
  union { float f; unsigned int i; } c; c.f = f;
  unsigned int u = c.i;
  return (u16)((u + 0x7FFFu + ((u >> 16) & 1u)) >> 16);
}
DEVINL unsigned pk2(float a, float b) {
  return (unsigned)f2bf(a) | ((unsigned)f2bf(b) << 16);
}
DEVINL float siluf(float x) { return x / (1.f + __expf(-x)); }

// ---------------- GCN graph part: CSR build + gather (no data atomics) ----------------

__global__ void degcnt_k(const int* __restrict__ ei, float* __restrict__ deg,
                         int* __restrict__ cnt) {
  int e = blockIdx.x * 256 + threadIdx.x;
  if (e < EE) {
    atomicAdd(&deg[ei[e]], 1.0f);        // src out-degree (for dis)
    atomicAdd(&cnt[ei[EE + e]], 1);      // dst in-degree (for CSR)
  }
}

__global__ void dis_k(float* __restrict__ deg) {
  int i = blockIdx.x * 256 + threadIdx.x;
  if (i < NN) deg[i] = rsqrtf(deg[i] + 1.0f);  // +1 self loop
}

__global__ __launch_bounds__(1024) void scan_k(const int* __restrict__ cnt,
    int* __restrict__ rowptr, int* __restrict__ cursor) {
  __shared__ int sm[1024];
  int t = threadIdx.x;
  int4 c = ((const int4*)cnt)[t];
  int tot = c.x + c.y + c.z + c.w;
  sm[t] = tot;
  __syncthreads();
  for (int off = 1; off < 1024; off <<= 1) {
    int v = (t >= off) ? sm[t - off] : 0;
    __syncthreads();
    sm[t] += v;
    __syncthreads();
  }
  int excl = sm[t] - tot;
  int4 r;
  r.x = excl; r.y = excl + c.x; r.z = r.y + c.y; r.w = r.z + c.z;
  ((int4*)rowptr)[t] = r;
  ((int4*)cursor)[t] = r;
  if (t == 1023) rowptr[4096] = excl + tot;
}

__global__ void fill_k(const int* __restrict__ ei, const float* __restrict__ dis,
    int* __restrict__ cursor, int* __restrict__ esrc, float* __restrict__ ew) {
  int e = blockIdx.x * 256 + threadIdx.x;
  if (e < EE) {
    int s = ei[e], t = ei[EE + e];
    int pos = atomicAdd(&cursor[t], 1);
    esrc[pos] = s;
    ew[pos] = dis[s];
  }
}

// one wave per dst node; lanes preload 64 (src,w) pairs, shfl-broadcast per edge
__global__ __launch_bounds__(256) void gather_k(const float* __restrict__ x,
    const float* __restrict__ dis, const int* __restrict__ rowptr,
    const int* __restrict__ esrc, const float* __restrict__ ew,
    float* __restrict__ aggr) {
  int node = blockIdx.x * 4 + (threadIdx.x >> 6);
  int lane = threadIdx.x & 63;
  int d0 = lane * 4;
  float dn = dis[node];
  const float4 xv = *(const float4*)(x + (size_t)node * DD + d0);
  float4 acc;  // accumulates dis[n]*x[n] + sum w*x[s]; final scale by dn
  acc.x = dn * xv.x; acc.y = dn * xv.y; acc.z = dn * xv.z; acc.w = dn * xv.w;
  int beg = rowptr[node], end = rowptr[node + 1];
  for (int base = beg; base < end; base += 64) {
    int idx = base + lane;
    int sv = (idx < end) ? esrc[idx] : 0;
    float wv = (idx < end) ? ew[idx] : 0.f;
    int chunk = min(64, end - base);
    int j = 0;
    for (; j + 2 <= chunk; j += 2) {
      int s0 = __shfl(sv, j), s1 = __shfl(sv, j + 1);
      float w0 = __shfl(wv, j), w1 = __shfl(wv, j + 1);
      const float4 v0 = *(const float4*)(x + (size_t)s0 * DD + d0);
      const float4 v1 = *(const float4*)(x + (size_t)s1 * DD + d0);
      acc.x = fmaf(w0, v0.x, acc.x); acc.y = fmaf(w0, v0.y, acc.y);
      acc.z = fmaf(w0, v0.z, acc.z); acc.w = fmaf(w0, v0.w, acc.w);
      acc.x = fmaf(w1, v1.x, acc.x); acc.y = fmaf(w1, v1.y, acc.y);
      acc.z = fmaf(w1, v1.z, acc.z); acc.w = fmaf(w1, v1.w, acc.w);
    }
    if (j < chunk) {
      int s0 = __shfl(sv, j);
      float w0 = __shfl(wv, j);
      const float4 v0 = *(const float4*)(x + (size_t)s0 * DD + d0);
      acc.x = fmaf(w0, v0.x, acc.x); acc.y = fmaf(w0, v0.y, acc.y);
      acc.z = fmaf(w0, v0.z, acc.z); acc.w = fmaf(w0, v0.w, acc.w);
    }
  }
  float4 outv;
  outv.x = dn * acc.x; outv.y = dn * acc.y; outv.z = dn * acc.z; outv.w = dn * acc.w;
  *(float4*)(aggr + (size_t)node * DD + d0) = outv;
}

// ---------------- bf16 MFMA GEMM: C[n,m] = A[n,k] @ W[m,k]^T ----------------

#define LSW(r, kb) ((((r) * 128 + ((kb) ^ (((r) & 7) << 4)))) >> 1)

template<bool SILU_A, bool SILU_OUT, bool ACCUM, bool A_BF16, bool W_SCALED>
__global__ __launch_bounds__(256) void mgemm(const void* __restrict__ Aptr,
    const float* __restrict__ W, const float* __restrict__ Wsc,
    const float* __restrict__ bias, float* __restrict__ C, int n, int m, int k)
{
  __shared__ u16 Al[128 * 64];
  __shared__ u16 Wl[64 * 64];
  const int tid = threadIdx.x;
  const int wid = tid >> 6, lane = tid & 63;
  const int wr = wid >> 1, wc = wid & 1;
  const int bn = blockIdx.x * 128, bm = blockIdx.y * 64;
  const int ar = tid >> 1, ak0 = (tid & 1) * 32;
  const int wrr = tid >> 2, wk0 = (tid & 3) * 16;

  f32x4 acc[4][2] = {};

  for (int kt = 0; kt < k; kt += 64) {
    if (A_BF16) {
      const u16* Ap = (const u16*)Aptr + (size_t)(bn + ar) * k + kt + ak0;
#pragma unroll
      for (int c = 0; c < 4; ++c) {
        uint4 w = *(const uint4*)(Ap + 8 * c);
        *(uint4*)&Al[LSW(ar, 2 * ak0 + 16 * c)] = w;
      }
    } else {
      const float* Ap = (const float*)Aptr + (size_t)(bn + ar) * k + kt + ak0;
#pragma unroll
      for (int c = 0; c < 4; ++c) {
        float4 u = *(const float4*)(Ap + 8 * c);
        float4 v = *(const float4*)(Ap + 8 * c + 4);
        if (SILU_A) {
          u.x = siluf(u.x); u.y = siluf(u.y); u.z = siluf(u.z); u.w = siluf(u.w);
          v.x = siluf(v.x); v.y = siluf(v.y); v.z = siluf(v.z); v.w = siluf(v.w);
        }
        uint4 w;
        w.x = pk2(u.x, u.y); w.y = pk2(u.z, u.w);
        w.z = pk2(v.x, v.y); w.w = pk2(v.z, v.w);
        *(uint4*)&Al[LSW(ar, 2 * ak0 + 16 * c)] = w;
      }
    }
    {
      const float* Wp = W + (size_t)(bm + wrr) * k + kt + wk0;
#pragma unroll
      for (int c = 0; c < 2; ++c) {
        float fv[8];
        *(float4*)&fv[0] = *(const float4*)(Wp + 8 * c);
        *(float4*)&fv[4] = *(const float4*)(Wp + 8 * c + 4);
        if (W_SCALED) {
          const float* scrow = Wsc + (size_t)(bm + wrr) * 256;
#pragma unroll
          for (int j = 0; j < 8; ++j) {
            unsigned kidx = (unsigned)(kt + wk0 + 8 * c + j);
            fv[j] *= scrow[(kidx * 9363u) >> 16];
          }
        }
        uint4 w;
        w.x = pk2(fv[0], fv[1]); w.y = pk2(fv[2], fv[3]);
        w.z = pk2(fv[4], fv[5]); w.w = pk2(fv[6], fv[7]);
        *(uint4*)&Wl[LSW(wrr, 2 * wk0 + 16 * c)] = w;
      }
    }
    __syncthreads();
#pragma unroll
    for (int kk = 0; kk < 64; kk += 32) {
      const int kb = (kk + (lane >> 4) * 8) * 2;
      bf8 av[4], bv[2];
#pragma unroll
      for (int fr = 0; fr < 4; ++fr) {
        int r = wr * 64 + fr * 16 + (lane & 15);
        av[fr] = *(const bf8*)&Al[LSW(r, kb)];
      }
#pragma unroll
      for (int fc = 0; fc < 2; ++fc) {
        int r = wc * 32 + fc * 16 + (lane & 15);
        bv[fc] = *(const bf8*)&Wl[LSW(r, kb)];
      }
#pragma unroll
      for (int fr = 0; fr < 4; ++fr)
#pragma unroll
        for (int fc = 0; fc < 2; ++fc)
          acc[fr][fc] = __builtin_amdgcn_mfma_f32_16x16x32_bf16(
              av[fr], bv[fc], acc[fr][fc], 0, 0, 0);
    }
    __syncthreads();
  }
#pragma unroll
  for (int fr = 0; fr < 4; ++fr)
#pragma unroll
    for (int fc = 0; fc < 2; ++fc) {
      int col = bm + wc * 32 + fc * 16 + (lane & 15);
      float bb = bias ? bias[col] : 0.f;
#pragma unroll
      for (int j = 0; j < 4; ++j) {
        int row = bn + wr * 64 + fr * 16 + (lane >> 4) * 4 + j;
        size_t idx = (size_t)row * m + col;
        float v = acc[fr][fc][j] + bb;
        if (ACCUM) v += C[idx];
        if (SILU_OUT) v = siluf(v);
        C[idx] = v;
      }
    }
}

// ---------------- LayerNorm ----------------

__global__ __launch_bounds__(256) void layernorm_k(const float* __restrict__ x,
    const float* __restrict__ g, const float* __restrict__ b, float* __restrict__ xn) {
  int row = blockIdx.x, t = threadIdx.x;
  float v = x[(size_t)row * DD + t];
  float s = v, sq = v * v;
#pragma unroll
  for (int o = 32; o > 0; o >>= 1) { s += __shfl_down(s, o); sq += __shfl_down(sq, o); }
  __shared__ float rs[4], rq[4];
  int wid = t >> 6, lane = t & 63;
  if (lane == 0) { rs[wid] = s; rq[wid] = sq; }
  __syncthreads();
  float S = rs[0] + rs[1] + rs[2] + rs[3];
  float SQ = rq[0] + rq[1] + rq[2] + rq[3];
  float mu = S * (1.f / 256.f);
  float var = SQ * (1.f / 256.f) - mu * mu;
  float inv = rsqrtf(var + 1e-5f);
  xn[(size_t)row * DD + t] = (v - mu) * inv * g[t] + b[t];
}

// ---------------- QKV fp32 -> bf16 (q-columns pre-scaled into exp2 domain) ----------------

__global__ __launch_bounds__(256) void cvtqkv_k(const float* __restrict__ in,
                                                u16* __restrict__ out) {
  int i = blockIdx.x * 256 + threadIdx.x;  // < N*768
  int col = i % 768;
  float v = in[i];
  if (col < 256) v *= 0.25500526764f;  // (1/sqrt(32)) * log2(e)
  out[i] = f2bf(v);
}

// ---------------- MFMA flash attention ----------------

__global__ __launch_bounds__(256) void flash3(const u16* __restrict__ qkv16,
                                              float* __restrict__ attno) {
  const int h = blockIdx.y, qb = blockIdx.x;
  const int tid = threadIdx.x, wid = tid >> 6;
  const int l15 = tid & 15, hi = (tid >> 4) & 3;
  __shared__ u16 Pf[4][2][64][8];

  const bf8 qf = *(const bf8*)(qkv16 +
      (size_t)(qb * 64 + wid * 16 + l15) * 768 + h * 32 + hi * 8);

  float m = -3.0e38f, l = 0.f;
  f32x4 oa0 = {}, oa1 = {};

  for (int t = 0; t < NN; t += 64) {
    f32x4 sc[4];
    const u16* kbase = qkv16 + (size_t)t * 768 + 256 + h * 32 + hi * 8;
#pragma unroll
    for (int f = 0; f < 4; ++f) {
      bf8 kf = *(const bf8*)(kbase + (size_t)(f * 16 + l15) * 768);
      f32x4 z = {};
      sc[f] = __builtin_amdgcn_mfma_f32_16x16x32_bf16(kf, qf, z, 0, 0, 0);
    }
    bf8 vf[2][2];
    const u16* vbase = qkv16 + (size_t)t * 768 + 512 + h * 32;
#pragma unroll
    for (int s = 0; s < 2; ++s)
#pragma unroll
      for (int a = 0; a < 2; ++a) {
        const u16* vp = vbase + (size_t)(s * 32 + hi * 8) * 768 + a * 16 + l15;
#pragma unroll
        for (int i = 0; i < 8; ++i) vf[s][a][i] = (short)vp[(size_t)i * 768];
      }
    float mx = sc[0][0];
#pragma unroll
    for (int f = 0; f < 4; ++f)
#pragma unroll
      for (int j = 0; j < 4; ++j) mx = fmaxf(mx, sc[f][j]);
    mx = fmaxf(mx, __shfl_xor(mx, 16));
    mx = fmaxf(mx, __shfl_xor(mx, 32));
    float mn = fmaxf(m, mx);
    float scale = exp2f(m - mn);
    m = mn;
    float sum = 0.f;
#pragma unroll
    for (int f = 0; f < 4; ++f)
#pragma unroll
      for (int j = 0; j < 4; ++j) { sc[f][j] = exp2f(sc[f][j] - mn); sum += sc[f][j]; }
    sum += __shfl_xor(sum, 16);
    sum += __shfl_xor(sum, 32);
    l = l * scale + sum;
#pragma unroll
    for (int j = 0; j < 4; ++j) {
      float scj = __shfl(scale, hi * 4 + j);
      oa0[j] *= scj; oa1[j] *= scj;
    }
#pragma unroll
    for (int f = 0; f < 4; ++f) {
      unsigned lo, hi2;
      asm("v_cvt_pk_bf16_f32 %0, %1, %2" : "=v"(lo) : "v"(sc[f][0]), "v"(sc[f][1]));
      asm("v_cvt_pk_bf16_f32 %0, %1, %2" : "=v"(hi2) : "v"(sc[f][2]), "v"(sc[f][3]));
      uint2 pr; pr.x = lo; pr.y = hi2;
      *(uint2*)&Pf[wid][f >> 1][l15 | (((f * 2 + (hi >> 1)) & 3) << 4)][(hi & 1) * 4] = pr;
    }
#pragma unroll
    for (int s = 0; s < 2; ++s) {
      bf8 pa = *(const bf8*)&Pf[wid][s][l15 | (hi << 4)][0];
      oa0 = __builtin_amdgcn_mfma_f32_16x16x32_bf16(pa, vf[s][0], oa0, 0, 0, 0);
      oa1 = __builtin_amdgcn_mfma_f32_16x16x32_bf16(pa, vf[s][1], oa1, 0, 0, 0);
    }
  }
#pragma unroll
  for (int j = 0; j < 4; ++j) {
    float lj = __shfl(l, hi * 4 + j);
    float inv = 1.f / lj;
    int q = qb * 64 + wid * 16 + hi * 4 + j;
    attno[(size_t)q * DD + h * 32 + l15] = oa0[j] * inv;
    attno[(size_t)q * DD + h * 32 + 16 + l15] = oa1[j] * inv;
  }
}

// ---------------- elementwise epilogues ----------------

__global__ __launch_bounds__(256) void ew_bn_res_k(float* __restrict__ io,
    const float* __restrict__ g, const float* __restrict__ b,
    const float* __restrict__ x, const float* __restrict__ extra) {
  int i = blockIdx.x * 256 + threadIdx.x;
  int d = i & 255;
  float s = g[d] * rsqrtf(1.0f + 1e-5f);
  float v = io[i] * s + b[d] + x[i];
  if (extra) v += extra[i];
  io[i] = v;
}

// ---------------- KAN: all 7 spline bases -> bf16 [N, D*7] ----------------

__global__ __launch_bounds__(256) void bspl_all_k(const float* __restrict__ h,
                                                  u16* __restrict__ bases) {
  int i = blockIdx.x * 256 + threadIdx.x;
  float v = h[i];
  float b[10];
#pragma unroll
  for (int j = 0; j < 10; ++j) {
    float g0 = 0.5f * j - 2.5f;
    b[j] = (v >= g0 && v < g0 + 0.5f) ? 1.f : 0.f;
  }
#pragma unroll
  for (int kk = 1; kk <= 3; ++kk) {
    float inv = 2.f / (float)kk;
#pragma unroll
    for (int j = 0; j + kk < 10; ++j) {
      float g0 = 0.5f * j - 2.5f;
      float g1 = 0.5f * (j + kk + 1) - 2.5f;
      b[j] = (v - g0) * inv * b[j] + (g1 - v) * inv * b[j + 1];
    }
  }
  u16* o = bases + (size_t)i * 7;
#pragma unroll
  for (int c = 0; c < 7; ++c) o[c] = f2bf(b[c]);
}

// ---------------- launcher ----------------

extern "C" void kernel_launch(void* const* d_in, const int* in_sizes, int n_in,
                              void* d_out, int out_size, void* d_ws, size_t ws_size,
                              hipStream_t stream) {
  const float* x      = (const float*)d_in[0];
  const int* ei       = (const int*)d_in[1];
  const float* gcn_w1 = (const float*)d_in[2];
  const float* gcn_b1 = (const float*)d_in[3];
  const float* gcn_w2 = (const float*)d_in[4];
  const float* gcn_b2 = (const float*)d_in[5];
  const float* ln_g   = (const float*)d_in[6];
  const float* ln_b   = (const float*)d_in[7];
  const float* w_qkv  = (const float*)d_in[8];
  const float* b_qkv  = (const float*)d_in[9];
  const float* w_o    = (const float*)d_in[10];
  const float* b_o    = (const float*)d_in[11];
  const float* a_w1   = (const float*)d_in[12];
  const float* a_b1   = (const float*)d_in[13];
  const float* a_w2   = (const float*)d_in[14];
  const float* a_b2   = (const float*)d_in[15];
  const float* bn1_g  = (const float*)d_in[16];
  const float* bn1_b  = (const float*)d_in[17];
  const float* bn2_g  = (const float*)d_in[18];
  const float* bn2_b  = (const float*)d_in[19];
  const float* k1_base = (const float*)d_in[20];
  const float* k1_spl  = (const float*)d_in[21];
  const float* k1_scl  = (const float*)d_in[22];
  const float* k2_base = (const float*)d_in[23];
  const float* k2_spl  = (const float*)d_in[24];
  const float* k2_scl  = (const float*)d_in[25];

  float* outF = (float*)d_out;

  const size_t ND = (size_t)NN * DD;
  const size_t BASES_F = 3670016;

  float* ws = (float*)d_ws;
  // CSR arrays
  float* dis    = ws;                          // [NN]
  int*   cnt    = (int*)(dis + NN);            // [NN]   (memset with dis)
  int*   rowptr = cnt + NN;                    // [NN+1]
  int*   cursor = rowptr + NN + 1;             // [NN]
  int*   esrc   = cursor + NN;                 // [EE]
  float* ew     = (float*)(esrc + EE);         // [EE]
  // big buffers
  float* R1   = ew + EE;                // [ND]     aggr -> attno
  float* R5   = R1 + ND;                // [2*ND]   mid; qkv-bf16 during attn window
  float* R4   = R5 + (size_t)NN * HIDN; // [ND]     xm
  float* R2   = R4 + ND;                // [ND]     xn -> o-out -> h1
  float* R3   = R2 + ND;                // [3.67M]  qkv fp32 -> bases(u16)
  float* R6   = R3 + BASES_F;           // [ND]     hbuf

  float* aggr = R1; float* attno = R1;
  float* mid  = R5; u16* qkv16 = (u16*)R5;
  float* xm   = R4;
  float* xn   = R2; float* h1 = R2;
  float* qkvb = R3; u16* bases = (u16*)R3;
  float* hbuf = R6;

  const dim3 B256(256);

  // ---- GCN aggregation via CSR gather ----
  hipMemsetAsync(dis, 0, NN * (sizeof(float) + sizeof(int)), stream);
  degcnt_k<<<EE / 256, B256, 0, stream>>>(ei, dis, cnt);
  dis_k<<<NN / 256, B256, 0, stream>>>(dis);
  scan_k<<<1, 1024, 0, stream>>>(cnt, rowptr, cursor);
  fill_k<<<EE / 256, B256, 0, stream>>>(ei, dis, cursor, esrc, ew);
  gather_k<<<NN / 4, B256, 0, stream>>>(x, dis, rowptr, esrc, ew, aggr);
  // ---- GCN MLP + BN + residual ----
  mgemm<false, true, false, false, false><<<dim3(32, HIDN / 64), B256, 0, stream>>>(
      aggr, gcn_w1, nullptr, gcn_b1, mid, NN, HIDN, DD);
  mgemm<false, false, false, false, false><<<dim3(32, DD / 64), B256, 0, stream>>>(
      mid, gcn_w2, nullptr, gcn_b2, xm, NN, DD, HIDN);
  ew_bn_res_k<<<ND / 256, B256, 0, stream>>>(xm, bn1_g, bn1_b, x, nullptr);

  // ---- attention branch ----
  layernorm_k<<<NN, B256, 0, stream>>>(x, ln_g, ln_b, xn);
  mgemm<false, false, false, false, false><<<dim3(32, 768 / 64), B256, 0, stream>>>(
      xn, w_qkv, nullptr, b_qkv, qkvb, NN, 3 * DD, DD);
  cvtqkv_k<<<(NN * 768) / 256, B256, 0, stream>>>(qkvb, qkv16);
  flash3<<<dim3(NN / 64, HHD), B256, 0, stream>>>(qkv16, attno);
  mgemm<false, false, false, false, false><<<dim3(32, DD / 64), B256, 0, stream>>>(
      attno, w_o, nullptr, b_o, xn, NN, DD, DD);
  mgemm<false, true, false, false, false><<<dim3(32, HIDN / 64), B256, 0, stream>>>(
      xn, a_w1, nullptr, a_b1, mid, NN, HIDN, DD);
  mgemm<false, false, false, false, false><<<dim3(32, DD / 64), B256, 0, stream>>>(
      mid, a_w2, nullptr, a_b2, hbuf, NN, DD, HIDN);
  ew_bn_res_k<<<ND / 256, B256, 0, stream>>>(hbuf, bn2_g, bn2_b, x, xm);  // hbuf = h

  // ---- KAN layer 1: h (hbuf) -> h1 ----
  bspl_all_k<<<ND / 256, B256, 0, stream>>>(hbuf, bases);
  mgemm<true, false, false, false, false><<<dim3(32, DD / 64), B256, 0, stream>>>(
      hbuf, k1_base, nullptr, nullptr, h1, NN, DD, DD);
  mgemm<false, false, true, true, true><<<dim3(32, DD / 64), B256, 0, stream>>>(
      bases, k1_spl, k1_scl, nullptr, h1, NN, DD, DD * COEF_);

  // ---- KAN layer 2: h1 -> d_out ----
  bspl_all_k<<<ND / 256, B256, 0, stream>>>(h1, bases);
  mgemm<true, false, false, false, false><<<dim3(32, DD / 64), B256, 0, stream>>>(
      h1, k2_base, nullptr, nullptr, outF, NN, DD, DD);
  mgemm<false, false, true, true, true><<<dim3(32, DD / 64), B256, 0, stream>>>(
      bases, k2_spl, k2_scl, nullptr, outF, NN, DD, DD * COEF_);
}

// Round 11
// 549.074 us; speedup vs baseline: 3.4033x; 1.0947x over previous
//
#include <hip/hip_runtime.h>

typedef unsigned short u16;
typedef __attribute__((ext_vector_type(8))) short bf8;   // 8 bf16 in 4 VGPRs
typedef __attribute__((ext_vector_type(4))) float f32x4;

#define DEVINL __device__ __forceinline__

constexpr int NN = 4096, DD = 256, EE = 131072, HHD = 8, HIDN = 512, COEF_ = 7;

DEVINL u16 f2bf(float f) {
  union { float f; unsigned int i; } c; c.f = f;
  unsigned int u = c.i;
  return (u16)((u + 0x7FFFu + ((u >> 16) & 1u)) >> 16);
}
DEVINL unsigned pk2(float a, float b) {
  return (unsigned)f2bf(a) | ((unsigned)f2bf(b) << 16);
}
DEVINL float siluf(float x) { return x / (1.f + __expf(-x)); }

// ---------------- GCN graph part: CSR build + gather (no data atomics) ----------------

__global__ void degcnt_k(const int* __restrict__ ei, float* __restrict__ deg,
                         int* __restrict__ cnt) {
  int e = blockIdx.x * 256 + threadIdx.x;
  if (e < EE) {
    atomicAdd(&deg[ei[e]], 1.0f);
    atomicAdd(&cnt[ei[EE + e]], 1);
  }
}

__global__ void dis_k(float* __restrict__ deg) {
  int i = blockIdx.x * 256 + threadIdx.x;
  if (i < NN) deg[i] = rsqrtf(deg[i] + 1.0f);  // +1 self loop
}

__global__ __launch_bounds__(1024) void scan_k(const int* __restrict__ cnt,
    int* __restrict__ rowptr, int* __restrict__ cursor) {
  __shared__ int sm[1024];
  int t = threadIdx.x;
  int4 c = ((const int4*)cnt)[t];
  int tot = c.x + c.y + c.z + c.w;
  sm[t] = tot;
  __syncthreads();
  for (int off = 1; off < 1024; off <<= 1) {
    int v = (t >= off) ? sm[t - off] : 0;
    __syncthreads();
    sm[t] += v;
    __syncthreads();
  }
  int excl = sm[t] - tot;
  int4 r;
  r.x = excl; r.y = excl + c.x; r.z = r.y + c.y; r.w = r.z + c.z;
  ((int4*)rowptr)[t] = r;
  ((int4*)cursor)[t] = r;
  if (t == 1023) rowptr[4096] = excl + tot;
}

__global__ void fill_k(const int* __restrict__ ei, const float* __restrict__ dis,
    int* __restrict__ cursor, int* __restrict__ esrc, float* __restrict__ ew) {
  int e = blockIdx.x * 256 + threadIdx.x;
  if (e < EE) {
    int s = ei[e], t = ei[EE + e];
    int pos = atomicAdd(&cursor[t], 1);
    esrc[pos] = s;
    ew[pos] = dis[s];
  }
}

__global__ __launch_bounds__(256) void gather_k(const float* __restrict__ x,
    const float* __restrict__ dis, const int* __restrict__ rowptr,
    const int* __restrict__ esrc, const float* __restrict__ ew,
    float* __restrict__ aggr) {
  int node = blockIdx.x * 4 + (threadIdx.x >> 6);
  int lane = threadIdx.x & 63;
  int d0 = lane * 4;
  float dn = dis[node];
  const float4 xv = *(const float4*)(x + (size_t)node * DD + d0);
  float4 acc;
  acc.x = dn * xv.x; acc.y = dn * xv.y; acc.z = dn * xv.z; acc.w = dn * xv.w;
  int beg = rowptr[node], end = rowptr[node + 1];
  for (int base = beg; base < end; base += 64) {
    int idx = base + lane;
    int sv = (idx < end) ? esrc[idx] : 0;
    float wv = (idx < end) ? ew[idx] : 0.f;
    int chunk = min(64, end - base);
    int j = 0;
    for (; j + 2 <= chunk; j += 2) {
      int s0 = __shfl(sv, j), s1 = __shfl(sv, j + 1);
      float w0 = __shfl(wv, j), w1 = __shfl(wv, j + 1);
      const float4 v0 = *(const float4*)(x + (size_t)s0 * DD + d0);
      const float4 v1 = *(const float4*)(x + (size_t)s1 * DD + d0);
      acc.x = fmaf(w0, v0.x, acc.x); acc.y = fmaf(w0, v0.y, acc.y);
      acc.z = fmaf(w0, v0.z, acc.z); acc.w = fmaf(w0, v0.w, acc.w);
      acc.x = fmaf(w1, v1.x, acc.x); acc.y = fmaf(w1, v1.y, acc.y);
      acc.z = fmaf(w1, v1.z, acc.z); acc.w = fmaf(w1, v1.w, acc.w);
    }
    if (j < chunk) {
      int s0 = __shfl(sv, j);
      float w0 = __shfl(wv, j);
      const float4 v0 = *(const float4*)(x + (size_t)s0 * DD + d0);
      acc.x = fmaf(w0, v0.x, acc.x); acc.y = fmaf(w0, v0.y, acc.y);
      acc.z = fmaf(w0, v0.z, acc.z); acc.w = fmaf(w0, v0.w, acc.w);
    }
  }
  float4 outv;
  outv.x = dn * acc.x; outv.y = dn * acc.y; outv.z = dn * acc.z; outv.w = dn * acc.w;
  *(float4*)(aggr + (size_t)node * DD + d0) = outv;
}

// ---------------- bf16 MFMA GEMM, 64x64 tile, reg-prefetch double buffer ----------------
// C[n,m] = A[n,k] @ W[m,k]^T. EP: 0=bias 1=bias+silu 2=(acc+bias)*bn+res(+extra) 3=qkv-bf16+Vt
// W_KAN: k>=256 region = spl[m][1792]*scl[m][256] (idx/7), k<256 = Wb[m][256].

#define LSW(r, kb) ((((r) * 128 + ((kb) ^ (((r) & 7) << 4)))) >> 1)

template<int EP, bool A_BF16, bool W_KAN>
__global__ __launch_bounds__(256) void mgemm(
    const void* __restrict__ Aptr, const float* __restrict__ Wb,
    const float* __restrict__ Wspl, const float* __restrict__ Wscl,
    const float* __restrict__ bias, const float* __restrict__ gam,
    const float* __restrict__ bet, const float* __restrict__ xres,
    const float* __restrict__ extra, float* __restrict__ C,
    u16* __restrict__ q16, u16* __restrict__ Vt, int n, int m, int k)
{
  __shared__ u16 Al[64 * 64];
  __shared__ u16 Wl[64 * 64];
  const int tid = threadIdx.x;
  const int wid = tid >> 6, lane = tid & 63;
  const int l15 = lane & 15, hi16 = lane >> 4;
  const int wr = wid >> 1, wc = wid & 1;
  const int bn = blockIdx.x * 64, bm = blockIdx.y * 64;
  const int sr = tid >> 2, sc0 = (tid & 3) * 16;

  float rAf[16];
  uint4 rAb[2];
  float rW[16];

  auto loadA = [&](int kt) {
    if (A_BF16) {
      const u16* Ap = (const u16*)Aptr + (size_t)(bn + sr) * k + kt + sc0;
      rAb[0] = *(const uint4*)Ap;
      rAb[1] = *(const uint4*)(Ap + 8);
    } else {
      const float* Ap = (const float*)Aptr + (size_t)(bn + sr) * k + kt + sc0;
#pragma unroll
      for (int c = 0; c < 4; ++c) *(float4*)&rAf[c * 4] = *(const float4*)(Ap + c * 4);
    }
  };
  auto loadW = [&](int kt) {
    if (W_KAN && kt >= 256) {
      int base = kt - 256 + sc0;
      const float* sp = Wspl + (size_t)(bm + sr) * 1792 + base;
      const float* sl = Wscl + (size_t)(bm + sr) * 256;
#pragma unroll
      for (int j = 0; j < 16; ++j) {
        unsigned idx = (unsigned)(base + j);
        rW[j] = sp[j] * sl[(idx * 9363u) >> 16];
      }
    } else {
      const float* Wp = Wb + (size_t)(bm + sr) * (W_KAN ? 256 : k) + kt + sc0;
#pragma unroll
      for (int c = 0; c < 4; ++c) *(float4*)&rW[c * 4] = *(const float4*)(Wp + c * 4);
    }
  };
  auto writeLDS = [&]() {
    if (A_BF16) {
      *(uint4*)&Al[LSW(sr, 2 * sc0)] = rAb[0];
      *(uint4*)&Al[LSW(sr, 2 * sc0 + 16)] = rAb[1];
    } else {
      uint4 w;
      w.x = pk2(rAf[0], rAf[1]);  w.y = pk2(rAf[2], rAf[3]);
      w.z = pk2(rAf[4], rAf[5]);  w.w = pk2(rAf[6], rAf[7]);
      *(uint4*)&Al[LSW(sr, 2 * sc0)] = w;
      w.x = pk2(rAf[8], rAf[9]);  w.y = pk2(rAf[10], rAf[11]);
      w.z = pk2(rAf[12], rAf[13]); w.w = pk2(rAf[14], rAf[15]);
      *(uint4*)&Al[LSW(sr, 2 * sc0 + 16)] = w;
    }
    uint4 w;
    w.x = pk2(rW[0], rW[1]);  w.y = pk2(rW[2], rW[3]);
    w.z = pk2(rW[4], rW[5]);  w.w = pk2(rW[6], rW[7]);
    *(uint4*)&Wl[LSW(sr, 2 * sc0)] = w;
    w.x = pk2(rW[8], rW[9]);  w.y = pk2(rW[10], rW[11]);
    w.z = pk2(rW[12], rW[13]); w.w = pk2(rW[14], rW[15]);
    *(uint4*)&Wl[LSW(sr, 2 * sc0 + 16)] = w;
  };

  f32x4 acc[2][2] = {};
  loadA(0); loadW(0);
  for (int kt = 0; kt < k; kt += 64) {
    __syncthreads();   // previous MFMA done reading LDS
    writeLDS();
    __syncthreads();
    if (kt + 64 < k) { loadA(kt + 64); loadW(kt + 64); }  // prefetch overlaps MFMA
#pragma unroll
    for (int kk = 0; kk < 64; kk += 32) {
      const int kb = (kk + hi16 * 8) * 2;
      bf8 av[2], bv[2];
      av[0] = *(const bf8*)&Al[LSW(wr * 32 + l15, kb)];
      av[1] = *(const bf8*)&Al[LSW(wr * 32 + 16 + l15, kb)];
      bv[0] = *(const bf8*)&Wl[LSW(wc * 32 + l15, kb)];
      bv[1] = *(const bf8*)&Wl[LSW(wc * 32 + 16 + l15, kb)];
      acc[0][0] = __builtin_amdgcn_mfma_f32_16x16x32_bf16(av[0], bv[0], acc[0][0], 0, 0, 0);
      acc[0][1] = __builtin_amdgcn_mfma_f32_16x16x32_bf16(av[0], bv[1], acc[0][1], 0, 0, 0);
      acc[1][0] = __builtin_amdgcn_mfma_f32_16x16x32_bf16(av[1], bv[0], acc[1][0], 0, 0, 0);
      acc[1][1] = __builtin_amdgcn_mfma_f32_16x16x32_bf16(av[1], bv[1], acc[1][1], 0, 0, 0);
    }
  }
  // epilogue: C/D col = lane&15, row = (lane>>4)*4 + j
#pragma unroll
  for (int fr = 0; fr < 2; ++fr)
#pragma unroll
    for (int fc = 0; fc < 2; ++fc) {
      int col = bm + wc * 32 + fc * 16 + l15;
      float bb = bias ? bias[col] : 0.f;
      float gs = 0.f, bt = 0.f;
      if (EP == 2) {
        gs = gam[col] * rsqrtf(1.f + 1e-5f);
        bt = bet[col];
      }
#pragma unroll
      for (int j = 0; j < 4; ++j) {
        int row = bn + wr * 32 + fr * 16 + hi16 * 4 + j;
        size_t idx = (size_t)row * m + col;
        float v = acc[fr][fc][j] + bb;
        if (EP == 1) v = siluf(v);
        if (EP == 2) {
          v = (acc[fr][fc][j] + bb) * gs + bt + xres[idx];
          if (extra) v += extra[idx];
        }
        if (EP == 3) {
          if (col < 256) q16[(size_t)row * 768 + col] = f2bf(v * 0.25500526764f);
          else if (col < 512) q16[(size_t)row * 768 + col] = f2bf(v);
          else Vt[(size_t)(col - 512) * 4096 + row] = f2bf(v);
        } else {
          C[idx] = v;
        }
      }
    }
}

// ---------------- LayerNorm -> bf16 ----------------

__global__ __launch_bounds__(256) void layernorm16_k(const float* __restrict__ x,
    const float* __restrict__ g, const float* __restrict__ b, u16* __restrict__ xn) {
  int row = blockIdx.x, t = threadIdx.x;
  float v = x[(size_t)row * DD + t];
  float s = v, sq = v * v;
#pragma unroll
  for (int o = 32; o > 0; o >>= 1) { s += __shfl_down(s, o); sq += __shfl_down(sq, o); }
  __shared__ float rs[4], rq[4];
  int wid = t >> 6, lane = t & 63;
  if (lane == 0) { rs[wid] = s; rq[wid] = sq; }
  __syncthreads();
  float S = rs[0] + rs[1] + rs[2] + rs[3];
  float SQ = rq[0] + rq[1] + rq[2] + rq[3];
  float mu = S * (1.f / 256.f);
  float var = SQ * (1.f / 256.f) - mu * mu;
  float inv = rsqrtf(var + 1e-5f);
  xn[(size_t)row * DD + t] = f2bf((v - mu) * inv * g[t] + b[t]);
}

// ---------------- MFMA flash attention (Vt for vector V loads) ----------------

__global__ __launch_bounds__(256) void flash3(const u16* __restrict__ qkv16,
                                              const u16* __restrict__ Vt,
                                              float* __restrict__ attno) {
  const int h = blockIdx.y, qb = blockIdx.x;
  const int tid = threadIdx.x, wid = tid >> 6;
  const int l15 = tid & 15, hi = (tid >> 4) & 3;
  __shared__ u16 Pf[4][2][64][8];

  const bf8 qf = *(const bf8*)(qkv16 +
      (size_t)(qb * 64 + wid * 16 + l15) * 768 + h * 32 + hi * 8);

  float m = -3.0e38f, l = 0.f;
  f32x4 oa0 = {}, oa1 = {};

  for (int t = 0; t < NN; t += 64) {
    f32x4 sc[4];
    const u16* kbase = qkv16 + (size_t)t * 768 + 256 + h * 32 + hi * 8;
#pragma unroll
    for (int f = 0; f < 4; ++f) {
      bf8 kf = *(const bf8*)(kbase + (size_t)(f * 16 + l15) * 768);
      f32x4 z = {};
      sc[f] = __builtin_amdgcn_mfma_f32_16x16x32_bf16(kf, qf, z, 0, 0, 0);
    }
    // V B-frags: contiguous 16B loads from Vt[d][n]
    bf8 vf[2][2];
    const u16* vtb = Vt + (size_t)(h * 32) * 4096 + t;
#pragma unroll
    for (int s = 0; s < 2; ++s)
#pragma unroll
      for (int a = 0; a < 2; ++a)
        vf[s][a] = *(const bf8*)(vtb + (size_t)(a * 16 + l15) * 4096 + s * 32 + hi * 8);
    float mx = sc[0][0];
#pragma unroll
    for (int f = 0; f < 4; ++f)
#pragma unroll
      for (int j = 0; j < 4; ++j) mx = fmaxf(mx, sc[f][j]);
    mx = fmaxf(mx, __shfl_xor(mx, 16));
    mx = fmaxf(mx, __shfl_xor(mx, 32));
    float mn = fmaxf(m, mx);
    float scale = exp2f(m - mn);
    m = mn;
    float sum = 0.f;
#pragma unroll
    for (int f = 0; f < 4; ++f)
#pragma unroll
      for (int j = 0; j < 4; ++j) { sc[f][j] = exp2f(sc[f][j] - mn); sum += sc[f][j]; }
    sum += __shfl_xor(sum, 16);
    sum += __shfl_xor(sum, 32);
    l = l * scale + sum;
#pragma unroll
    for (int j = 0; j < 4; ++j) {
      float scj = __shfl(scale, hi * 4 + j);
      oa0[j] *= scj; oa1[j] *= scj;
    }
#pragma unroll
    for (int f = 0; f < 4; ++f) {
      unsigned lo, hi2;
      asm("v_cvt_pk_bf16_f32 %0, %1, %2" : "=v"(lo) : "v"(sc[f][0]), "v"(sc[f][1]));
      asm("v_cvt_pk_bf16_f32 %0, %1, %2" : "=v"(hi2) : "v"(sc[f][2]), "v"(sc[f][3]));
      uint2 pr; pr.x = lo; pr.y = hi2;
      *(uint2*)&Pf[wid][f >> 1][l15 | (((f * 2 + (hi >> 1)) & 3) << 4)][(hi & 1) * 4] = pr;
    }
#pragma unroll
    for (int s = 0; s < 2; ++s) {
      bf8 pa = *(const bf8*)&Pf[wid][s][l15 | (hi << 4)][0];
      oa0 = __builtin_amdgcn_mfma_f32_16x16x32_bf16(pa, vf[s][0], oa0, 0, 0, 0);
      oa1 = __builtin_amdgcn_mfma_f32_16x16x32_bf16(pa, vf[s][1], oa1, 0, 0, 0);
    }
  }
#pragma unroll
  for (int j = 0; j < 4; ++j) {
    float lj = __shfl(l, hi * 4 + j);
    float inv = 1.f / lj;
    int q = qb * 64 + wid * 16 + hi * 4 + j;
    attno[(size_t)q * DD + h * 32 + l15] = oa0[j] * inv;
    attno[(size_t)q * DD + h * 32 + 16 + l15] = oa1[j] * inv;
  }
}

// ---------------- KAN: cat = [silu(h) | 7 spline bases] bf16 [N][2048] ----------------

__global__ __launch_bounds__(256) void bsplcat_k(const float* __restrict__ h,
                                                 u16* __restrict__ cat) {
  int i = blockIdx.x * 256 + threadIdx.x;  // < N*D
  float v = h[i];
  int row = i >> 8, col = i & 255;
  u16* crow = cat + (size_t)row * 2048;
  crow[col] = f2bf(siluf(v));
  float b[10];
#pragma unroll
  for (int j = 0; j < 10; ++j) {
    float g0 = 0.5f * j - 2.5f;
    b[j] = (v >= g0 && v < g0 + 0.5f) ? 1.f : 0.f;
  }
#pragma unroll
  for (int kk = 1; kk <= 3; ++kk) {
    float inv = 2.f / (float)kk;
#pragma unroll
    for (int j = 0; j + kk < 10; ++j) {
      float g0 = 0.5f * j - 2.5f;
      float g1 = 0.5f * (j + kk + 1) - 2.5f;
      b[j] = (v - g0) * inv * b[j] + (g1 - v) * inv * b[j + 1];
    }
  }
  u16* o = crow + 256 + col * 7;
#pragma unroll
  for (int c = 0; c < 7; ++c) o[c] = f2bf(b[c]);
}

// ---------------- launcher ----------------

extern "C" void kernel_launch(void* const* d_in, const int* in_sizes, int n_in,
                              void* d_out, int out_size, void* d_ws, size_t ws_size,
                              hipStream_t stream) {
  const float* x      = (const float*)d_in[0];
  const int* ei       = (const int*)d_in[1];
  const float* gcn_w1 = (const float*)d_in[2];
  const float* gcn_b1 = (const float*)d_in[3];
  const float* gcn_w2 = (const float*)d_in[4];
  const float* gcn_b2 = (const float*)d_in[5];
  const float* ln_g   = (const float*)d_in[6];
  const float* ln_b   = (const float*)d_in[7];
  const float* w_qkv  = (const float*)d_in[8];
  const float* b_qkv  = (const float*)d_in[9];
  const float* w_o    = (const float*)d_in[10];
  const float* b_o    = (const float*)d_in[11];
  const float* a_w1   = (const float*)d_in[12];
  const float* a_b1   = (const float*)d_in[13];
  const float* a_w2   = (const float*)d_in[14];
  const float* a_b2   = (const float*)d_in[15];
  const float* bn1_g  = (const float*)d_in[16];
  const float* bn1_b  = (const float*)d_in[17];
  const float* bn2_g  = (const float*)d_in[18];
  const float* bn2_b  = (const float*)d_in[19];
  const float* k1_base = (const float*)d_in[20];
  const float* k1_spl  = (const float*)d_in[21];
  const float* k1_scl  = (const float*)d_in[22];
  const float* k2_base = (const float*)d_in[23];
  const float* k2_spl  = (const float*)d_in[24];
  const float* k2_scl  = (const float*)d_in[25];

  float* outF = (float*)d_out;

  const size_t ND = (size_t)NN * DD;

  float* ws = (float*)d_ws;
  float* dis    = ws;                          // [NN]
  int*   cnt    = (int*)(dis + NN);            // [NN]
  int*   rowptr = cnt + NN;                    // [NN+1]
  int*   cursor = rowptr + NN + 1;             // [NN]
  int*   esrc   = cursor + NN;                 // [EE]
  float* ew     = (float*)(esrc + EE);         // [EE]
  float* R1 = ew + EE;                  // [ND]   aggr -> attno
  float* R5 = R1 + ND;                  // [2*ND] mid
  float* R4 = R5 + 2 * ND;              // [ND]   xm
  float* R2 = R4 + ND;                  // [ND]   xn16(u16) -> oproj -> h1
  float* R3 = R2 + ND;                  // [4*ND] qkv16+Vt -> cat [N][2048] u16
  float* R6 = R3 + 4 * ND;              // [ND]   hbuf

  float* aggr = R1; float* attno = R1;
  float* mid  = R5;
  float* xm   = R4;
  u16* xn16   = (u16*)R2; float* oproj = R2; float* h1 = R2;
  u16* qkv16  = (u16*)R3;
  u16* Vt     = (u16*)R3 + (size_t)NN * 768;
  u16* cat    = (u16*)R3;
  float* hbuf = R6;

  const dim3 B256(256);
  const float* np = nullptr;
  float* nf = nullptr;
  u16* nu = nullptr;

  // ---- GCN aggregation via CSR gather ----
  (void)hipMemsetAsync(dis, 0, NN * (sizeof(float) + sizeof(int)), stream);
  degcnt_k<<<EE / 256, B256, 0, stream>>>(ei, dis, cnt);
  dis_k<<<NN / 256, B256, 0, stream>>>(dis);
  scan_k<<<1, 1024, 0, stream>>>(cnt, rowptr, cursor);
  fill_k<<<EE / 256, B256, 0, stream>>>(ei, dis, cursor, esrc, ew);
  gather_k<<<NN / 4, B256, 0, stream>>>(x, dis, rowptr, esrc, ew, aggr);
  // ---- GCN MLP + fused BN/residual ----
  mgemm<1, false, false><<<dim3(64, 8), B256, 0, stream>>>(
      aggr, gcn_w1, np, np, gcn_b1, np, np, np, np, mid, nu, nu, NN, HIDN, DD);
  mgemm<2, false, false><<<dim3(64, 4), B256, 0, stream>>>(
      mid, gcn_w2, np, np, gcn_b2, bn1_g, bn1_b, x, np, xm, nu, nu, NN, DD, HIDN);

  // ---- attention branch ----
  layernorm16_k<<<NN, B256, 0, stream>>>(x, ln_g, ln_b, xn16);
  mgemm<3, true, false><<<dim3(64, 12), B256, 0, stream>>>(
      xn16, w_qkv, np, np, b_qkv, np, np, np, np, nf, qkv16, Vt, NN, 768, DD);
  flash3<<<dim3(NN / 64, HHD), B256, 0, stream>>>(qkv16, Vt, attno);
  mgemm<0, false, false><<<dim3(64, 4), B256, 0, stream>>>(
      attno, w_o, np, np, b_o, np, np, np, np, oproj, nu, nu, NN, DD, DD);
  mgemm<1, false, false><<<dim3(64, 8), B256, 0, stream>>>(
      oproj, a_w1, np, np, a_b1, np, np, np, np, mid, nu, nu, NN, HIDN, DD);
  mgemm<2, false, false><<<dim3(64, 4), B256, 0, stream>>>(
      mid, a_w2, np, np, a_b2, bn2_g, bn2_b, x, xm, hbuf, nu, nu, NN, DD, HIDN);

  // ---- KAN layer 1 ----
  bsplcat_k<<<ND / 256, B256, 0, stream>>>(hbuf, cat);
  mgemm<0, true, true><<<dim3(64, 4), B256, 0, stream>>>(
      cat, k1_base, k1_spl, k1_scl, np, np, np, np, np, h1, nu, nu, NN, DD, 2048);
  // ---- KAN layer 2 ----
  bsplcat_k<<<ND / 256, B256, 0, stream>>>(h1, cat);
  mgemm<0, true, true><<<dim3(64, 4), B256, 0, stream>>>(
      cat, k2_base, k2_spl, k2_scl, np, np, np, np, np, outF, nu, nu, NN, DD, 2048);
}

// Round 12
// 545.195 us; speedup vs baseline: 3.4275x; 1.0071x over previous
//
#include <hip/hip_runtime.h>

typedef unsigned short u16;
typedef __attribute__((ext_vector_type(8))) short bf8;   // 8 bf16 in 4 VGPRs
typedef __attribute__((ext_vector_type(4))) float f32x4;

#define DEVINL __device__ __forceinline__

constexpr int NN = 4096, DD = 256, EE = 131072, HHD = 8, HIDN = 512, COEF_ = 7;

DEVINL u16 f2bf(float f) {
  union { float f; unsigned int i; } c; c.f = f;
  unsigned int u = c.i;
  return (u16)((u + 0x7FFFu + ((u >> 16) & 1u)) >> 16);
}
DEVINL unsigned pk2(float a, float b) {
  return (unsigned)f2bf(a) | ((unsigned)f2bf(b) << 16);
}
DEVINL float siluf(float x) { return x / (1.f + __expf(-x)); }

// ---------------- GCN graph part: CSR build + gather (no data atomics) ----------------

__global__ void degcnt_k(const int* __restrict__ ei, float* __restrict__ deg,
                         int* __restrict__ cnt) {
  int e = blockIdx.x * 256 + threadIdx.x;
  if (e < EE) {
    atomicAdd(&deg[ei[e]], 1.0f);
    atomicAdd(&cnt[ei[EE + e]], 1);
  }
}

__global__ void dis_k(float* __restrict__ deg) {
  int i = blockIdx.x * 256 + threadIdx.x;
  if (i < NN) deg[i] = rsqrtf(deg[i] + 1.0f);  // +1 self loop
}

__global__ __launch_bounds__(1024) void scan_k(const int* __restrict__ cnt,
    int* __restrict__ rowptr, int* __restrict__ cursor) {
  __shared__ int sm[1024];
  int t = threadIdx.x;
  int4 c = ((const int4*)cnt)[t];
  int tot = c.x + c.y + c.z + c.w;
  sm[t] = tot;
  __syncthreads();
  for (int off = 1; off < 1024; off <<= 1) {
    int v = (t >= off) ? sm[t - off] : 0;
    __syncthreads();
    sm[t] += v;
    __syncthreads();
  }
  int excl = sm[t] - tot;
  int4 r;
  r.x = excl; r.y = excl + c.x; r.z = r.y + c.y; r.w = r.z + c.z;
  ((int4*)rowptr)[t] = r;
  ((int4*)cursor)[t] = r;
  if (t == 1023) rowptr[4096] = excl + tot;
}

__global__ void fill_k(const int* __restrict__ ei, const float* __restrict__ dis,
    int* __restrict__ cursor, int* __restrict__ esrc, float* __restrict__ ew) {
  int e = blockIdx.x * 256 + threadIdx.x;
  if (e < EE) {
    int s = ei[e], t = ei[EE + e];
    int pos = atomicAdd(&cursor[t], 1);
    esrc[pos] = s;
    ew[pos] = dis[s];
  }
}

__global__ __launch_bounds__(256) void gather_k(const float* __restrict__ x,
    const float* __restrict__ dis, const int* __restrict__ rowptr,
    const int* __restrict__ esrc, const float* __restrict__ ew,
    float* __restrict__ aggr) {
  int node = blockIdx.x * 4 + (threadIdx.x >> 6);
  int lane = threadIdx.x & 63;
  int d0 = lane * 4;
  float dn = dis[node];
  const float4 xv = *(const float4*)(x + (size_t)node * DD + d0);
  float4 acc;
  acc.x = dn * xv.x; acc.y = dn * xv.y; acc.z = dn * xv.z; acc.w = dn * xv.w;
  int beg = rowptr[node], end = rowptr[node + 1];
  for (int base = beg; base < end; base += 64) {
    int idx = base + lane;
    int sv = (idx < end) ? esrc[idx] : 0;
    float wv = (idx < end) ? ew[idx] : 0.f;
    int chunk = min(64, end - base);
    int j = 0;
    for (; j + 2 <= chunk; j += 2) {
      int s0 = __shfl(sv, j), s1 = __shfl(sv, j + 1);
      float w0 = __shfl(wv, j), w1 = __shfl(wv, j + 1);
      const float4 v0 = *(const float4*)(x + (size_t)s0 * DD + d0);
      const float4 v1 = *(const float4*)(x + (size_t)s1 * DD + d0);
      acc.x = fmaf(w0, v0.x, acc.x); acc.y = fmaf(w0, v0.y, acc.y);
      acc.z = fmaf(w0, v0.z, acc.z); acc.w = fmaf(w0, v0.w, acc.w);
      acc.x = fmaf(w1, v1.x, acc.x); acc.y = fmaf(w1, v1.y, acc.y);
      acc.z = fmaf(w1, v1.z, acc.z); acc.w = fmaf(w1, v1.w, acc.w);
    }
    if (j < chunk) {
      int s0 = __shfl(sv, j);
      float w0 = __shfl(wv, j);
      const float4 v0 = *(const float4*)(x + (size_t)s0 * DD + d0);
      acc.x = fmaf(w0, v0.x, acc.x); acc.y = fmaf(w0, v0.y, acc.y);
      acc.z = fmaf(w0, v0.z, acc.z); acc.w = fmaf(w0, v0.w, acc.w);
    }
  }
  float4 outv;
  outv.x = dn * acc.x; outv.y = dn * acc.y; outv.z = dn * acc.z; outv.w = dn * acc.w;
  *(float4*)(aggr + (size_t)node * DD + d0) = outv;
}

// ---------------- bf16 MFMA GEMM, 64x64 tile, 2-deep register prefetch ----------------
// C[n,m] = A[n,k] @ W[m,k]^T. EP: 0=bias 1=bias+silu 2=(acc+bias)*bn+res(+extra) 3=qkv-bf16+Vt
// W_KAN: k>=256 region = spl[m][1792]*scl[m][256] (idx/7), k<256 = Wb[m][256].
// k must be a multiple of 128 (all uses: 256, 512, 2048).

#define LSW(r, kb) ((((r) * 128 + ((kb) ^ (((r) & 7) << 4)))) >> 1)

template<int EP, bool A_BF16, bool W_KAN>
__global__ __launch_bounds__(256) void mgemm(
    const void* __restrict__ Aptr, const float* __restrict__ Wb,
    const float* __restrict__ Wspl, const float* __restrict__ Wscl,
    const float* __restrict__ bias, const float* __restrict__ gam,
    const float* __restrict__ bet, const float* __restrict__ xres,
    const float* __restrict__ extra, float* __restrict__ C,
    u16* __restrict__ q16, u16* __restrict__ Vt, int n, int m, int k)
{
  __shared__ u16 Al[64 * 64];
  __shared__ u16 Wl[64 * 64];
  const int tid = threadIdx.x;
  const int wid = tid >> 6, lane = tid & 63;
  const int l15 = lane & 15, hi16 = lane >> 4;
  const int wr = wid >> 1, wc = wid & 1;
  const int bn = blockIdx.x * 64, bm = blockIdx.y * 64;
  const int sr = tid >> 2, sc0 = (tid & 3) * 16;

  float rAf[2][16];
  uint4 rAb[2][2];
  float rW[2][16];

#define MG_LOADA(S, KT) do {                                                    \
    if (A_BF16) {                                                               \
      const u16* Ap = (const u16*)Aptr + (size_t)(bn + sr) * k + (KT) + sc0;    \
      rAb[S][0] = *(const uint4*)Ap;                                            \
      rAb[S][1] = *(const uint4*)(Ap + 8);                                      \
    } else {                                                                    \
      const float* Ap = (const float*)Aptr + (size_t)(bn + sr) * k + (KT) + sc0;\
      _Pragma("unroll")                                                         \
      for (int c = 0; c < 4; ++c)                                               \
        *(float4*)&rAf[S][c * 4] = *(const float4*)(Ap + c * 4);                \
    }                                                                           \
  } while (0)

#define MG_LOADW(S, KT) do {                                                    \
    if (W_KAN && (KT) >= 256) {                                                 \
      int base = (KT) - 256 + sc0;                                              \
      const float* sp = Wspl + (size_t)(bm + sr) * 1792 + base;                 \
      const float* sl = Wscl + (size_t)(bm + sr) * 256;                         \
      _Pragma("unroll")                                                         \
      for (int j = 0; j < 16; ++j) {                                            \
        unsigned idx = (unsigned)(base + j);                                    \
        rW[S][j] = sp[j] * sl[(idx * 9363u) >> 16];                             \
      }                                                                         \
    } else {                                                                    \
      const float* Wp = Wb + (size_t)(bm + sr) * (W_KAN ? 256 : k) + (KT) + sc0;\
      _Pragma("unroll")                                                         \
      for (int c = 0; c < 4; ++c)                                               \
        *(float4*)&rW[S][c * 4] = *(const float4*)(Wp + c * 4);                 \
    }                                                                           \
  } while (0)

#define MG_WRITE(S) do {                                                        \
    if (A_BF16) {                                                               \
      *(uint4*)&Al[LSW(sr, 2 * sc0)] = rAb[S][0];                               \
      *(uint4*)&Al[LSW(sr, 2 * sc0 + 16)] = rAb[S][1];                          \
    } else {                                                                    \
      uint4 w;                                                                  \
      w.x = pk2(rAf[S][0], rAf[S][1]);  w.y = pk2(rAf[S][2], rAf[S][3]);        \
      w.z = pk2(rAf[S][4], rAf[S][5]);  w.w = pk2(rAf[S][6], rAf[S][7]);        \
      *(uint4*)&Al[LSW(sr, 2 * sc0)] = w;                                       \
      w.x = pk2(rAf[S][8], rAf[S][9]);  w.y = pk2(rAf[S][10], rAf[S][11]);      \
      w.z = pk2(rAf[S][12], rAf[S][13]); w.w = pk2(rAf[S][14], rAf[S][15]);     \
      *(uint4*)&Al[LSW(sr, 2 * sc0 + 16)] = w;                                  \
    }                                                                           \
    uint4 w;                                                                    \
    w.x = pk2(rW[S][0], rW[S][1]);  w.y = pk2(rW[S][2], rW[S][3]);              \
    w.z = pk2(rW[S][4], rW[S][5]);  w.w = pk2(rW[S][6], rW[S][7]);              \
    *(uint4*)&Wl[LSW(sr, 2 * sc0)] = w;                                         \
    w.x = pk2(rW[S][8], rW[S][9]);  w.y = pk2(rW[S][10], rW[S][11]);            \
    w.z = pk2(rW[S][12], rW[S][13]); w.w = pk2(rW[S][14], rW[S][15]);           \
    *(uint4*)&Wl[LSW(sr, 2 * sc0 + 16)] = w;                                    \
  } while (0)

#define MG_MFMA() do {                                                          \
    _Pragma("unroll")                                                           \
    for (int kk = 0; kk < 64; kk += 32) {                                       \
      const int kb = (kk + hi16 * 8) * 2;                                       \
      bf8 av[2], bv[2];                                                         \
      av[0] = *(const bf8*)&Al[LSW(wr * 32 + l15, kb)];                         \
      av[1] = *(const bf8*)&Al[LSW(wr * 32 + 16 + l15, kb)];                    \
      bv[0] = *(const bf8*)&Wl[LSW(wc * 32 + l15, kb)];                         \
      bv[1] = *(const bf8*)&Wl[LSW(wc * 32 + 16 + l15, kb)];                    \
      acc[0][0] = __builtin_amdgcn_mfma_f32_16x16x32_bf16(av[0], bv[0], acc[0][0], 0, 0, 0); \
      acc[0][1] = __builtin_amdgcn_mfma_f32_16x16x32_bf16(av[0], bv[1], acc[0][1], 0, 0, 0); \
      acc[1][0] = __builtin_amdgcn_mfma_f32_16x16x32_bf16(av[1], bv[0], acc[1][0], 0, 0, 0); \
      acc[1][1] = __builtin_amdgcn_mfma_f32_16x16x32_bf16(av[1], bv[1], acc[1][1], 0, 0, 0); \
    }                                                                           \
  } while (0)

  f32x4 acc[2][2] = {};
  MG_LOADA(0, 0); MG_LOADW(0, 0);
  MG_LOADA(1, 64); MG_LOADW(1, 64);
  for (int kt = 0; kt < k; kt += 128) {
    __syncthreads();
    MG_WRITE(0);
    __syncthreads();
    if (kt + 128 < k) { MG_LOADA(0, kt + 128); MG_LOADW(0, kt + 128); }
    MG_MFMA();
    __syncthreads();
    MG_WRITE(1);
    __syncthreads();
    if (kt + 192 < k) { MG_LOADA(1, kt + 192); MG_LOADW(1, kt + 192); }
    MG_MFMA();
  }
  // epilogue: C/D col = lane&15, row = (lane>>4)*4 + j
#pragma unroll
  for (int fr = 0; fr < 2; ++fr)
#pragma unroll
    for (int fc = 0; fc < 2; ++fc) {
      int col = bm + wc * 32 + fc * 16 + l15;
      float bb = bias ? bias[col] : 0.f;
      float gs = 0.f, bt = 0.f;
      if (EP == 2) {
        gs = gam[col] * rsqrtf(1.f + 1e-5f);
        bt = bet[col];
      }
#pragma unroll
      for (int j = 0; j < 4; ++j) {
        int row = bn + wr * 32 + fr * 16 + hi16 * 4 + j;
        size_t idx = (size_t)row * m + col;
        float v = acc[fr][fc][j] + bb;
        if (EP == 1) v = siluf(v);
        if (EP == 2) {
          v = (acc[fr][fc][j] + bb) * gs + bt + xres[idx];
          if (extra) v += extra[idx];
        }
        if (EP == 3) {
          if (col < 256) q16[(size_t)row * 768 + col] = f2bf(v * 0.25500526764f);
          else if (col < 512) q16[(size_t)row * 768 + col] = f2bf(v);
          else Vt[(size_t)(col - 512) * 4096 + row] = f2bf(v);
        } else {
          C[idx] = v;
        }
      }
    }
}

// ---------------- LayerNorm -> bf16 ----------------

__global__ __launch_bounds__(256) void layernorm16_k(const float* __restrict__ x,
    const float* __restrict__ g, const float* __restrict__ b, u16* __restrict__ xn) {
  int row = blockIdx.x, t = threadIdx.x;
  float v = x[(size_t)row * DD + t];
  float s = v, sq = v * v;
#pragma unroll
  for (int o = 32; o > 0; o >>= 1) { s += __shfl_down(s, o); sq += __shfl_down(sq, o); }
  __shared__ float rs[4], rq[4];
  int wid = t >> 6, lane = t & 63;
  if (lane == 0) { rs[wid] = s; rq[wid] = sq; }
  __syncthreads();
  float S = rs[0] + rs[1] + rs[2] + rs[3];
  float SQ = rq[0] + rq[1] + rq[2] + rq[3];
  float mu = S * (1.f / 256.f);
  float var = SQ * (1.f / 256.f) - mu * mu;
  float inv = rsqrtf(var + 1e-5f);
  xn[(size_t)row * DD + t] = f2bf((v - mu) * inv * g[t] + b[t]);
}

// ---------------- MFMA flash attention, software-pipelined K/V prefetch ----------------

__global__ __launch_bounds__(256) void flash3(const u16* __restrict__ qkv16,
                                              const u16* __restrict__ Vt,
                                              float* __restrict__ attno) {
  const int h = blockIdx.y, qb = blockIdx.x;
  const int tid = threadIdx.x, wid = tid >> 6;
  const int l15 = tid & 15, hi = (tid >> 4) & 3;
  __shared__ u16 Pf[4][2][64][8];

  const bf8 qf = *(const bf8*)(qkv16 +
      (size_t)(qb * 64 + wid * 16 + l15) * 768 + h * 32 + hi * 8);

  float m = -3.0e38f, l = 0.f;
  f32x4 oa0 = {}, oa1 = {};

  bf8 kf[2][4], vf[2][4];
  // prologue: load tile 0 K/V frags
  {
    const u16* kb0 = qkv16 + 256 + h * 32 + hi * 8;
#pragma unroll
    for (int f = 0; f < 4; ++f)
      kf[0][f] = *(const bf8*)(kb0 + (size_t)(f * 16 + l15) * 768);
    const u16* vb0 = Vt + (size_t)(h * 32) * 4096;
#pragma unroll
    for (int s = 0; s < 2; ++s)
#pragma unroll
      for (int a = 0; a < 2; ++a)
        vf[0][s * 2 + a] = *(const bf8*)(vb0 + (size_t)(a * 16 + l15) * 4096 + s * 32 + hi * 8);
  }

#define FLASH_TILE(CUR, NXT, T) {                                               \
    f32x4 sc[4];                                                                \
    _Pragma("unroll")                                                           \
    for (int f = 0; f < 4; ++f) {                                               \
      f32x4 z = {};                                                             \
      sc[f] = __builtin_amdgcn_mfma_f32_16x16x32_bf16(kf[CUR][f], qf, z, 0, 0, 0); \
    }                                                                           \
    int tn = ((T) + 64 < NN) ? (T) + 64 : 0;                                    \
    const u16* kb2 = qkv16 + (size_t)tn * 768 + 256 + h * 32 + hi * 8;          \
    _Pragma("unroll")                                                           \
    for (int f = 0; f < 4; ++f)                                                 \
      kf[NXT][f] = *(const bf8*)(kb2 + (size_t)(f * 16 + l15) * 768);           \
    const u16* vb2 = Vt + (size_t)(h * 32) * 4096 + tn;                         \
    _Pragma("unroll")                                                           \
    for (int s = 0; s < 2; ++s)                                                 \
      _Pragma("unroll")                                                         \
      for (int a = 0; a < 2; ++a)                                               \
        vf[NXT][s * 2 + a] = *(const bf8*)(vb2 + (size_t)(a * 16 + l15) * 4096 + s * 32 + hi * 8); \
    float mx = sc[0][0];                                                        \
    _Pragma("unroll")                                                           \
    for (int f = 0; f < 4; ++f)                                                 \
      _Pragma("unroll")                                                         \
      for (int j = 0; j < 4; ++j) mx = fmaxf(mx, sc[f][j]);                     \
    mx = fmaxf(mx, __shfl_xor(mx, 16));                                         \
    mx = fmaxf(mx, __shfl_xor(mx, 32));                                         \
    float mn = fmaxf(m, mx);                                                    \
    float scale = exp2f(m - mn);                                                \
    m = mn;                                                                     \
    float sum = 0.f;                                                            \
    _Pragma("unroll")                                                           \
    for (int f = 0; f < 4; ++f)                                                 \
      _Pragma("unroll")                                                         \
      for (int j = 0; j < 4; ++j) { sc[f][j] = exp2f(sc[f][j] - mn); sum += sc[f][j]; } \
    sum += __shfl_xor(sum, 16);                                                 \
    sum += __shfl_xor(sum, 32);                                                 \
    l = l * scale + sum;                                                        \
    _Pragma("unroll")                                                           \
    for (int j = 0; j < 4; ++j) {                                               \
      float scj = __shfl(scale, hi * 4 + j);                                    \
      oa0[j] *= scj; oa1[j] *= scj;                                             \
    }                                                                           \
    _Pragma("unroll")                                                           \
    for (int f = 0; f < 4; ++f) {                                               \
      unsigned lo, hi2;                                                         \
      asm("v_cvt_pk_bf16_f32 %0, %1, %2" : "=v"(lo) : "v"(sc[f][0]), "v"(sc[f][1])); \
      asm("v_cvt_pk_bf16_f32 %0, %1, %2" : "=v"(hi2) : "v"(sc[f][2]), "v"(sc[f][3])); \
      uint2 pr; pr.x = lo; pr.y = hi2;                                          \
      *(uint2*)&Pf[wid][f >> 1][l15 | (((f * 2 + (hi >> 1)) & 3) << 4)][(hi & 1) * 4] = pr; \
    }                                                                           \
    _Pragma("unroll")                                                           \
    for (int s = 0; s < 2; ++s) {                                               \
      bf8 pa = *(const bf8*)&Pf[wid][s][l15 | (hi << 4)][0];                    \
      oa0 = __builtin_amdgcn_mfma_f32_16x16x32_bf16(pa, vf[CUR][s * 2 + 0], oa0, 0, 0, 0); \
      oa1 = __builtin_amdgcn_mfma_f32_16x16x32_bf16(pa, vf[CUR][s * 2 + 1], oa1, 0, 0, 0); \
    }                                                                           \
  }

  for (int t = 0; t < NN; t += 128) {
    FLASH_TILE(0, 1, t)
    FLASH_TILE(1, 0, t + 64)
  }

#pragma unroll
  for (int j = 0; j < 4; ++j) {
    float lj = __shfl(l, hi * 4 + j);
    float inv = 1.f / lj;
    int q = qb * 64 + wid * 16 + hi * 4 + j;
    attno[(size_t)q * DD + h * 32 + l15] = oa0[j] * inv;
    attno[(size_t)q * DD + h * 32 + 16 + l15] = oa1[j] * inv;
  }
}

// ---------------- KAN: cat = [silu(h) | 7 spline bases] bf16 [N][2048] ----------------

__global__ __launch_bounds__(256) void bsplcat_k(const float* __restrict__ h,
                                                 u16* __restrict__ cat) {
  int i = blockIdx.x * 256 + threadIdx.x;  // < N*D
  float v = h[i];
  int row = i >> 8, col = i & 255;
  u16* crow = cat + (size_t)row * 2048;
  crow[col] = f2bf(siluf(v));
  float b[10];
#pragma unroll
  for (int j = 0; j < 10; ++j) {
    float g0 = 0.5f * j - 2.5f;
    b[j] = (v >= g0 && v < g0 + 0.5f) ? 1.f : 0.f;
  }
#pragma unroll
  for (int kk = 1; kk <= 3; ++kk) {
    float inv = 2.f / (float)kk;
#pragma unroll
    for (int j = 0; j + kk < 10; ++j) {
      float g0 = 0.5f * j - 2.5f;
      float g1 = 0.5f * (j + kk + 1) - 2.5f;
      b[j] = (v - g0) * inv * b[j] + (g1 - v) * inv * b[j + 1];
    }
  }
  u16* o = crow + 256 + col * 7;
#pragma unroll
  for (int c = 0; c < 7; ++c) o[c] = f2bf(b[c]);
}

// ---------------- launcher ----------------

extern "C" void kernel_launch(void* const* d_in, const int* in_sizes, int n_in,
                              void* d_out, int out_size, void* d_ws, size_t ws_size,
                              hipStream_t stream) {
  const float* x      = (const float*)d_in[0];
  const int* ei       = (const int*)d_in[1];
  const float* gcn_w1 = (const float*)d_in[2];
  const float* gcn_b1 = (const float*)d_in[3];
  const float* gcn_w2 = (const float*)d_in[4];
  const float* gcn_b2 = (const float*)d_in[5];
  const float* ln_g   = (const float*)d_in[6];
  const float* ln_b   = (const float*)d_in[7];
  const float* w_qkv  = (const float*)d_in[8];
  const float* b_qkv  = (const float*)d_in[9];
  const float* w_o    = (const float*)d_in[10];
  const float* b_o    = (const float*)d_in[11];
  const float* a_w1   = (const float*)d_in[12];
  const float* a_b1   = (const float*)d_in[13];
  const float* a_w2   = (const float*)d_in[14];
  const float* a_b2   = (const float*)d_in[15];
  const float* bn1_g  = (const float*)d_in[16];
  const float* bn1_b  = (const float*)d_in[17];
  const float* bn2_g  = (const float*)d_in[18];
  const float* bn2_b  = (const float*)d_in[19];
  const float* k1_base = (const float*)d_in[20];
  const float* k1_spl  = (const float*)d_in[21];
  const float* k1_scl  = (const float*)d_in[22];
  const float* k2_base = (const float*)d_in[23];
  const float* k2_spl  = (const float*)d_in[24];
  const float* k2_scl  = (const float*)d_in[25];

  float* outF = (float*)d_out;

  const size_t ND = (size_t)NN * DD;

  float* ws = (float*)d_ws;
  float* dis    = ws;                          // [NN]
  int*   cnt    = (int*)(dis + NN);            // [NN]
  int*   rowptr = cnt + NN;                    // [NN+1]
  int*   cursor = rowptr + NN + 1;             // [NN]
  int*   esrc   = cursor + NN;                 // [EE]
  float* ew     = (float*)(esrc + EE);         // [EE]
  float* R1 = ew + EE;                  // [ND]   aggr -> attno
  float* R5 = R1 + ND;                  // [2*ND] mid
  float* R4 = R5 + 2 * ND;              // [ND]   xm
  float* R2 = R4 + ND;                  // [ND]   xn16(u16) -> oproj -> h1
  float* R3 = R2 + ND;                  // [4*ND] qkv16+Vt -> cat [N][2048] u16
  float* R6 = R3 + 4 * ND;              // [ND]   hbuf

  float* aggr = R1; float* attno = R1;
  float* mid  = R5;
  float* xm   = R4;
  u16* xn16   = (u16*)R2; float* oproj = R2; float* h1 = R2;
  u16* qkv16  = (u16*)R3;
  u16* Vt     = (u16*)R3 + (size_t)NN * 768;
  u16* cat    = (u16*)R3;
  float* hbuf = R6;

  const dim3 B256(256);
  const float* np = nullptr;
  float* nf = nullptr;
  u16* nu = nullptr;

  // ---- GCN aggregation via CSR gather ----
  (void)hipMemsetAsync(dis, 0, NN * (sizeof(float) + sizeof(int)), stream);
  degcnt_k<<<EE / 256, B256, 0, stream>>>(ei, dis, cnt);
  dis_k<<<NN / 256, B256, 0, stream>>>(dis);
  scan_k<<<1, 1024, 0, stream>>>(cnt, rowptr, cursor);
  fill_k<<<EE / 256, B256, 0, stream>>>(ei, dis, cursor, esrc, ew);
  gather_k<<<NN / 4, B256, 0, stream>>>(x, dis, rowptr, esrc, ew, aggr);
  // ---- GCN MLP + fused BN/residual ----
  mgemm<1, false, false><<<dim3(64, 8), B256, 0, stream>>>(
      aggr, gcn_w1, np, np, gcn_b1, np, np, np, np, mid, nu, nu, NN, HIDN, DD);
  mgemm<2, false, false><<<dim3(64, 4), B256, 0, stream>>>(
      mid, gcn_w2, np, np, gcn_b2, bn1_g, bn1_b, x, np, xm, nu, nu, NN, DD, HIDN);

  // ---- attention branch ----
  layernorm16_k<<<NN, B256, 0, stream>>>(x, ln_g, ln_b, xn16);
  mgemm<3, true, false><<<dim3(64, 12), B256, 0, stream>>>(
      xn16, w_qkv, np, np, b_qkv, np, np, np, np, nf, qkv16, Vt, NN, 768, DD);
  flash3<<<dim3(NN / 64, HHD), B256, 0, stream>>>(qkv16, Vt, attno);
  mgemm<0, false, false><<<dim3(64, 4), B256, 0, stream>>>(
      attno, w_o, np, np, b_o, np, np, np, np, oproj, nu, nu, NN, DD, DD);
  mgemm<1, false, false><<<dim3(64, 8), B256, 0, stream>>>(
      oproj, a_w1, np, np, a_b1, np, np, np, np, mid, nu, nu, NN, HIDN, DD);
  mgemm<2, false, false><<<dim3(64, 4), B256, 0, stream>>>(
      mid, a_w2, np, np, a_b2, bn2_g, bn2_b, x, xm, hbuf, nu, nu, NN, DD, HIDN);

  // ---- KAN layer 1 ----
  bsplcat_k<<<ND / 256, B256, 0, stream>>>(hbuf, cat);
  mgemm<0, true, true><<<dim3(64, 4), B256, 0, stream>>>(
      cat, k1_base, k1_spl, k1_scl, np, np, np, np, np, h1, nu, nu, NN, DD, 2048);
  // ---- KAN layer 2 ----
  bsplcat_k<<<ND / 256, B256, 0, stream>>>(h1, cat);
  mgemm<0, true, true><<<dim3(64, 4), B256, 0, stream>>>(
      cat, k2_base, k2_spl, k2_scl, np, np, np, np, np, outF, nu, nu, NN, DD, 2048);
}